// Round 3
// baseline (60.991 us; speedup 1.0000x reference)
//
#include <hip/hip_runtime.h>

// Causal quadratic linear attention, chunked-scan formulation.
//   (q.k)^2 = sum_{i,j} q_i q_j k_i k_j   (256 ordered-pair features, F = 16i+j)
// Phases: p01 (fused convert + per-chunk state G, e-split over 2 blocks),
//         p2p (fully-parallel exclusive chunk prefix -> Hb),
//         p3  (state apply + intra-chunk causal; 16q x 32d per wave).

#define SEQN 4096
#define NHEAD 8
#define DKEY 16
#define DVAL 64
#define CHUNK 256
#define NCHUNK 16
#define ALPHA 0.03125f
#define VT2S 264    // bf16 row stride (16B-aligned)
#define KTFS 268    // f32 row stride

typedef float f32x4 __attribute__((ext_vector_type(4)));
typedef __bf16 bf16x8 __attribute__((ext_vector_type(8)));
typedef __bf16 bf16x2 __attribute__((ext_vector_type(2)));
typedef unsigned long long u64;
typedef u64 u64x2 __attribute__((ext_vector_type(2)));

__device__ inline float bf2f(__bf16 x) {
    unsigned short u = __builtin_bit_cast(unsigned short, x);
    unsigned int v = ((unsigned int)u) << 16;
    return __builtin_bit_cast(float, v);
}

// ---------------- Phase 01: convert K/V + per-chunk state G^T[e][f] ----------------
// grid: (h, c, eh2) = 256 blocks x 256 thr.
// eh2=0: e rows 0..31  (V dims 0..31);  writes Kbf + Vtg d 0..31;  2 et MFMA groups
// eh2=1: e rows 32..79 (V dims 32..63, ones row 64, pad); Vtg d 32..63; 3 et groups
__global__ __launch_bounds__(256, 1)
void p01_state(const float* __restrict__ Kg, const float* __restrict__ Vg,
               __bf16* __restrict__ Kbf, __bf16* __restrict__ Vtg,
               __bf16* __restrict__ G)
{
    __shared__ __align__(16) __bf16 Vt2[48 * VT2S];
    __shared__ __align__(16) float  Ktf[16 * KTFS];
    const int tid = threadIdx.x;
    const int w = tid >> 6;
    const int lane = tid & 63;
    const int r = lane & 15, g = lane >> 4;
    const int bid = blockIdx.x;
    const int h = bid & 7, c = (bid >> 3) & 15, eh2 = bid >> 7;
    const int k0 = c * CHUNK;
    const int net = eh2 ? 3 : 2;

    // ---- stage K transposed (all 16 dims x 256 t) + Kbf (eh2==0 only) ----
    {
        const int t = tid;
        const float* kp = Kg + ((size_t)h * SEQN + k0 + t) * DKEY;
        f32x4 kv[4];
        #pragma unroll
        for (int m = 0; m < 4; ++m) kv[m] = *(const f32x4*)(kp + 4 * m);
        #pragma unroll
        for (int m = 0; m < 4; ++m)
            #pragma unroll
            for (int j = 0; j < 4; ++j)
                Ktf[(4 * m + j) * KTFS + t] = kv[m][j];
        if (eh2 == 0) {
            bf16x8 o0, o1;
            #pragma unroll
            for (int j = 0; j < 4; ++j) {
                o0[j] = (__bf16)kv[0][j]; o0[4 + j] = (__bf16)kv[1][j];
                o1[j] = (__bf16)kv[2][j]; o1[4 + j] = (__bf16)kv[3][j];
            }
            __bf16* ko = Kbf + ((size_t)h * SEQN + k0 + t) * DKEY;
            *(bf16x8*)ko = o0;
            *(bf16x8*)(ko + 8) = o1;
        }
    }
    // ---- stage V rows (32 dims per half), local row = dim - 32*eh2 ----
    {
        const int el = tid & 31;             // local row
        const int seg = tid >> 5;            // 0..7
        const int dim = 32 * eh2 + el;
        const float* __restrict__ Vh = Vg + (size_t)h * SEQN * DVAL;
        #pragma unroll
        for (int p = 0; p < 4; ++p) {
            const int tb = 8 * (seg + 8 * p);
            bf16x8 v;
            #pragma unroll
            for (int j = 0; j < 8; ++j)
                v[j] = (__bf16)Vh[(size_t)(k0 + tb + j) * DVAL + dim];
            *(bf16x8*)&Vt2[el * VT2S + tb] = v;
        }
    }
    // ---- ones + pad rows (eh2==1: local rows 32..47) ----
    if (eh2 == 1) {
        Vt2[32 * VT2S + tid] = (__bf16)1.0f;
        #pragma unroll
        for (int rr = 33; rr < 48; ++rr) Vt2[rr * VT2S + tid] = (__bf16)0.0f;
    }
    __syncthreads();

    // ---- Vtg write-out: permuted V^T rows (static u64-granular permutation) ----
    {
        const int kt_l = tid >> 6;           // 0..3
        const int dloc = tid & 63;
        if (dloc < 32) {
            u64 tmp[16];
            #pragma unroll
            for (int s = 0; s < 16; ++s)
                tmp[s] = *(const u64*)&Vt2[dloc * VT2S + kt_l * 64 + 4 * s];
            u64 o[16];
            #pragma unroll
            for (int hi = 0; hi < 2; ++hi)
                #pragma unroll
                for (int uk = 0; uk < 2; ++uk)
                    #pragma unroll
                    for (int gp = 0; gp < 4; ++gp)
                        o[hi * 8 + 2 * gp + uk] = tmp[hi * 8 + 4 * uk + gp];
            __bf16* vo = Vtg + ((size_t)((h * 64 + c * 4 + kt_l) * 64 + 32 * eh2 + dloc)) * 64;
            #pragma unroll
            for (int m = 0; m < 8; ++m) {
                u64x2 pp; pp[0] = o[2 * m]; pp[1] = o[2 * m + 1];
                *(u64x2*)((u64*)vo + 2 * m) = pp;
            }
        }
    }

    // ---- MFMA: G^T[e][f] = V'^T x Phi ----
    f32x4 acc[4][3] = {};
    #pragma unroll
    for (int ks = 0; ks < 8; ++ks) {
        const int t0 = 32 * ks + 8 * g;
        bf16x8 af[3];
        #pragma unroll
        for (int etl = 0; etl < 3; ++etl)
            if (etl < net)
                af[etl] = *(const bf16x8*)&Vt2[(16 * etl + r) * VT2S + t0];
        const f32x4 kra = *(const f32x4*)&Ktf[r * KTFS + t0];
        const f32x4 krb = *(const f32x4*)&Ktf[r * KTFS + t0 + 4];
        #pragma unroll
        for (int ftl = 0; ftl < 4; ++ftl) {
            const int ft = 4 * w + ftl;
            const f32x4 kfa = *(const f32x4*)&Ktf[ft * KTFS + t0];
            const f32x4 kfb = *(const f32x4*)&Ktf[ft * KTFS + t0 + 4];
            bf16x8 bfrag;
            #pragma unroll
            for (int j = 0; j < 4; ++j) {
                bfrag[j]     = (__bf16)(kfa[j] * kra[j]);
                bfrag[4 + j] = (__bf16)(kfb[j] * krb[j]);
            }
            #pragma unroll
            for (int etl = 0; etl < 3; ++etl)
                if (etl < net)
                    acc[ftl][etl] = __builtin_amdgcn_mfma_f32_16x16x32_bf16(
                        af[etl], bfrag, acc[ftl][etl], 0, 0, 0);
        }
    }
    // ---- write G[h][c][e][f] ----
    __bf16* Gc = G + (size_t)((h * NCHUNK + c) * 80) * 256;
    #pragma unroll
    for (int ftl = 0; ftl < 4; ++ftl) {
        const int f = 16 * (4 * w + ftl) + r;
        #pragma unroll
        for (int etl = 0; etl < 3; ++etl)
            if (etl < net) {
                #pragma unroll
                for (int i = 0; i < 4; ++i) {
                    const int e = 32 * eh2 + 16 * etl + 4 * g + i;
                    Gc[e * 256 + f] = (__bf16)acc[ftl][etl][i];
                }
            }
    }
}

// ---------------- Phase 2: fully-parallel exclusive chunk prefix ----------------
// grid: (h, c, fb) = 8*16*80 = 10240 blocks x 256 thr; Hb[h][c][.] = sum_{cc<c} G[h][cc][.]
__global__ void p2_prefix(const __bf16* __restrict__ G, __bf16* __restrict__ Hb)
{
    const int fb = blockIdx.x % 80;
    const int hc = blockIdx.x / 80;
    const int c = hc & 15, h = hc >> 4;
    const int fid = fb * 256 + threadIdx.x;
    float acc = 0.f;
    for (int cc = 0; cc < c; ++cc)
        acc += bf2f(G[(size_t)(h * NCHUNK + cc) * 20480 + fid]);
    Hb[(size_t)(h * NCHUNK + c) * 20480 + fid] = (__bf16)acc;
}

// ---------------- Phase 3: state apply + intra-chunk causal ----------------
// grid: (h, qs16, eh) = 8*256*2 = 4096 blocks x 64 thr.
// Each wave: 16 queries, output dims 32*eh..32*eh+31 (+Z if eh==0).
__global__ __launch_bounds__(64)
void p3_attend(const float* __restrict__ Qg, const __bf16* __restrict__ Kbf,
               const __bf16* __restrict__ Vtg, const __bf16* __restrict__ Hb,
               float* __restrict__ Og)
{
    const int lane = threadIdx.x;
    const int r = lane & 15, g = lane >> 4;
    const int bid = blockIdx.x;
    const int h = bid & 7;
    const int qs = (bid >> 3) & 255;
    const int eh = bid >> 11;
    const int qb = qs * 16;
    const int c = qs >> 4;

    // q row (fp32)
    float qr[16];
    {
        const float* qp = Qg + ((size_t)h * SEQN + qb + r) * DKEY;
        #pragma unroll
        for (int m = 0; m < 4; ++m) {
            const f32x4 v = *(const f32x4*)(qp + 4 * m);
            qr[4 * m + 0] = v[0]; qr[4 * m + 1] = v[1];
            qr[4 * m + 2] = v[2]; qr[4 * m + 3] = v[3];
        }
    }
    float qsel[8];
    #pragma unroll
    for (int j = 0; j < 8; ++j) qsel[j] = (g & 1) ? qr[8 + j] : qr[j];
    bf16x8 qfrag = {};
    if (g < 2) {
        #pragma unroll
        for (int j = 0; j < 8; ++j) qfrag[j] = (__bf16)qsel[j];
    }

    f32x4 oacc[2] = {};
    f32x4 zacc4 = {};
    float zin = 0.f;

    // ---- state apply: O += Psi(q) x H_{<c} ----
    if (c > 0) {
        const __bf16* Hc = Hb + (size_t)((h * NCHUNK + c) * 80) * 256;
        #pragma unroll
        for (int ks = 0; ks < 8; ++ks) {
            const int t0 = 32 * ks + 8 * g;
            const bf16x8 af0 = *(const bf16x8*)&Hc[(16 * (2 * eh + 0) + r) * 256 + t0];
            const bf16x8 af1 = *(const bf16x8*)&Hc[(16 * (2 * eh + 1) + r) * 256 + t0];
            bf16x8 afz;
            if (eh == 0) afz = *(const bf16x8*)&Hc[(64 + r) * 256 + t0];
            const float qi = ALPHA * ((g & 2) ? qr[2 * ks + 1] : qr[2 * ks]);
            bf16x8 pf;
            #pragma unroll
            for (int j = 0; j < 8; ++j) pf[j] = (__bf16)(qi * qsel[j]);
            oacc[0] = __builtin_amdgcn_mfma_f32_16x16x32_bf16(af0, pf, oacc[0], 0, 0, 0);
            oacc[1] = __builtin_amdgcn_mfma_f32_16x16x32_bf16(af1, pf, oacc[1], 0, 0, 0);
            if (eh == 0)
                zacc4 = __builtin_amdgcn_mfma_f32_16x16x32_bf16(afz, pf, zacc4, 0, 0, 0);
        }
    }

    // ---- intra-chunk causal tiles ----
    const int ktmax = qs >> 2;
    for (int kt = 4 * c; kt <= ktmax; ++kt) {
        const int k0 = kt * 64;
        const bool diag = (kt == ktmax);
        const __bf16* Vb = Vtg + (size_t)((h * 64 + kt) * 64) * 64;
        #pragma unroll
        for (int ks = 0; ks < 2; ++ks) {
            if (k0 + 32 * ks < qb + 16) {
                bf16x8 kf[2];
                #pragma unroll
                for (int uk = 0; uk < 2; ++uk) {
                    bf16x8 f = {};
                    if (g < 2)
                        f = *(const bf16x8*)&Kbf[((size_t)h * SEQN + k0 + 32 * ks + 16 * uk + r) * DKEY + 8 * g];
                    kf[uk] = f;
                }
                bf16x8 vf[2];
                #pragma unroll
                for (int dtl = 0; dtl < 2; ++dtl)
                    vf[dtl] = *(const bf16x8*)&Vb[(size_t)(16 * (2 * eh + dtl) + r) * 64 + 32 * ks + 8 * g];

                const f32x4 zero4 = {};
                f32x4 s[2];
                #pragma unroll
                for (int uk = 0; uk < 2; ++uk)
                    s[uk] = __builtin_amdgcn_mfma_f32_16x16x32_bf16(
                        kf[uk], qfrag, zero4, 0, 0, 0);

                bf16x8 pf;
                float zs = 0.f;
                const int qG = qb + r;
                #pragma unroll
                for (int uk = 0; uk < 2; ++uk) {
                    const int kGb = k0 + 32 * ks + 16 * uk + 4 * g;
                    #pragma unroll
                    for (int i = 0; i < 4; ++i) {
                        const float sv = s[uk][i];
                        float p = ALPHA * sv * sv;
                        if (diag && (kGb + i > qG)) p = 0.f;
                        zs += p;
                        pf[4 * uk + i] = (__bf16)p;
                    }
                }
                zin += zs;
                #pragma unroll
                for (int dtl = 0; dtl < 2; ++dtl)
                    oacc[dtl] = __builtin_amdgcn_mfma_f32_16x16x32_bf16(
                        vf[dtl], pf, oacc[dtl], 0, 0, 0);
            }
        }
    }

    // ---- stores ----
    const int q = qb + r;
    #pragma unroll
    for (int dtl = 0; dtl < 2; ++dtl) {
        float* op = Og + ((size_t)h * SEQN + q) * DVAL + 16 * (2 * eh + dtl) + 4 * g;
        *(f32x4*)op = oacc[dtl];
    }
    if (eh == 0) {
        zin += __shfl_xor(zin, 16); zin += __shfl_xor(zin, 32);
        if (lane < 16) {
            float* zp = Og + (size_t)NHEAD * SEQN * DVAL + (size_t)h * SEQN + qb;
            zp[r] = zin + zacc4[0];
        }
    }
}

// ---------------- Fallback (monolithic) if workspace too small ----------------
__global__ __launch_bounds__(128, 2)
void taylor_mono(const float* __restrict__ Qg, const float* __restrict__ Kg,
                 const float* __restrict__ Vg, float* __restrict__ Og)
{
    __shared__ __align__(16) __bf16 Kl[64 * 32];
    __shared__ __align__(16) __bf16 Vt[64 * 72];
    const int tid = threadIdx.x;
    const int wv = tid >> 6;
    const int lane = tid & 63;
    const int r = lane & 15, g = lane >> 4;
    const int bid = blockIdx.x;
    const int h = bid & 7;
    const int tt = bid >> 3;
    const int qt = (tt & 1) ? (tt >> 1) : (63 - (tt >> 1));
    const int qb = qt * 64 + wv * 32;
    const float* __restrict__ Qh = Qg + (size_t)h * SEQN * DKEY;
    const float* __restrict__ Kh = Kg + (size_t)h * SEQN * DKEY;
    const float* __restrict__ Vh = Vg + (size_t)h * SEQN * DVAL;
    for (int row = tid; row < 64; row += 128) {
        bf16x8 z = {};
        *(bf16x8*)&Kl[row * 32 + 16] = z;
        *(bf16x8*)&Kl[row * 32 + 24] = z;
    }
    bf16x8 qfrag[2];
    #pragma unroll
    for (int uq = 0; uq < 2; ++uq) {
        bf16x8 f = {};
        if (g < 2) {
            const float* qp = Qh + (size_t)(qb + 16 * uq + r) * DKEY + 8 * g;
            const f32x4 a = *(const f32x4*)qp;
            const f32x4 b = *(const f32x4*)(qp + 4);
            #pragma unroll
            for (int j = 0; j < 4; ++j) { f[j] = (__bf16)a[j]; f[4 + j] = (__bf16)b[j]; }
        }
        qfrag[uq] = f;
    }
    f32x4 oacc[2][4] = {};
    float zacc0 = 0.f, zacc1 = 0.f;
    const int nkt = qt + 1;
    for (int kt = 0; kt < nkt; ++kt) {
        const int k0 = kt * 64;
        {
            const int key = tid >> 1, half = tid & 1;
            const float* kp = Kh + (size_t)(k0 + key) * DKEY + 8 * half;
            const f32x4 a = *(const f32x4*)kp;
            const f32x4 b = *(const f32x4*)(kp + 4);
            bf16x8 kb;
            #pragma unroll
            for (int j = 0; j < 4; ++j) { kb[j] = (__bf16)a[j]; kb[4 + j] = (__bf16)b[j]; }
            *(bf16x8*)&Kl[key * 32 + 8 * half] = kb;
        }
        {
            const int d = tid & 63;
            const int kp2 = (tid >> 6) * 2;
            #pragma unroll
            for (int i = 0; i < 16; ++i) {
                const int kk = i * 4 + kp2;
                const float a0 = Vh[(size_t)(k0 + kk) * DVAL + d];
                const float a1 = Vh[(size_t)(k0 + kk + 1) * DVAL + d];
                const int w32 = kk & 31;
                const int col = (kk & 32) + ((w32 >> 2) & 3) * 8 + ((w32 >> 4) << 2) + (kk & 3);
                bf16x2 p; p[0] = (__bf16)a0; p[1] = (__bf16)a1;
                *(bf16x2*)&Vt[d * 72 + col] = p;
            }
        }
        __syncthreads();
        const bool diag = (kt + 1 == nkt);
        #pragma unroll
        for (int ks = 0; ks < 2; ++ks) {
            if (k0 + 32 * ks < qb + 32) {
                bf16x8 vfrag[4];
                #pragma unroll
                for (int dt = 0; dt < 4; ++dt)
                    vfrag[dt] = *(const bf16x8*)&Vt[(16 * dt + r) * 72 + 32 * ks + 8 * g];
                bf16x8 kf[2];
                #pragma unroll
                for (int uk = 0; uk < 2; ++uk)
                    kf[uk] = *(const bf16x8*)&Kl[(32 * ks + 16 * uk + r) * 32 + 8 * g];
                const f32x4 zero4 = {};
                f32x4 s[2][2];
                #pragma unroll
                for (int uq = 0; uq < 2; ++uq)
                    #pragma unroll
                    for (int uk = 0; uk < 2; ++uk)
                        s[uq][uk] = __builtin_amdgcn_mfma_f32_16x16x32_bf16(
                            kf[uk], qfrag[uq], zero4, 0, 0, 0);
                #pragma unroll
                for (int uq = 0; uq < 2; ++uq) {
                    bf16x8 pf;
                    float zs = 0.f;
                    #pragma unroll
                    for (int uk = 0; uk < 2; ++uk) {
                        const int kGb = k0 + 32 * ks + 16 * uk + 4 * g;
                        const int qG = qb + 16 * uq + r;
                        #pragma unroll
                        for (int i = 0; i < 4; ++i) {
                            const float sv = s[uq][uk][i];
                            float p = 0.03125f * sv * sv;
                            if (diag && (kGb + i > qG)) p = 0.f;
                            zs += p;
                            pf[4 * uk + i] = (__bf16)p;
                        }
                    }
                    if (uq == 0) zacc0 += zs; else zacc1 += zs;
                    #pragma unroll
                    for (int dt = 0; dt < 4; ++dt)
                        oacc[uq][dt] = __builtin_amdgcn_mfma_f32_16x16x32_bf16(
                            vfrag[dt], pf, oacc[uq][dt], 0, 0, 0);
                }
            }
        }
        __syncthreads();
    }
    #pragma unroll
    for (int uq = 0; uq < 2; ++uq) {
        const int q = qb + 16 * uq + r;
        #pragma unroll
        for (int dt = 0; dt < 4; ++dt) {
            float* op = Og + ((size_t)h * SEQN + q) * DVAL + 16 * dt + 4 * g;
            *(f32x4*)op = oacc[uq][dt];
        }
    }
    zacc0 += __shfl_xor(zacc0, 16); zacc0 += __shfl_xor(zacc0, 32);
    zacc1 += __shfl_xor(zacc1, 16); zacc1 += __shfl_xor(zacc1, 32);
    if (lane < 16) {
        float* zp = Og + (size_t)NHEAD * SEQN * DVAL + (size_t)h * SEQN + qb;
        zp[r] = zacc0;
        zp[16 + r] = zacc1;
    }
}

extern "C" void kernel_launch(void* const* d_in, const int* in_sizes, int n_in,
                              void* d_out, int out_size, void* d_ws, size_t ws_size,
                              hipStream_t stream) {
    const float* Q = (const float*)d_in[0];
    const float* K = (const float*)d_in[1];
    const float* V = (const float*)d_in[2];
    float* O = (float*)d_out;

    const size_t G_OFF   = 0;                      // 8*16*80*256 bf16 = 5,242,880 B
    const size_t HB_OFF  = 5242880;
    const size_t KBF_OFF = 10485760;               // 8*4096*16 bf16 = 1,048,576 B
    const size_t VTG_OFF = 11534336;               // 8*64*64*64 bf16 = 4,194,304 B
    const size_t NEED    = 15728640;

    if (ws_size >= NEED) {
        char* ws = (char*)d_ws;
        __bf16* G   = (__bf16*)(ws + G_OFF);
        __bf16* Hb  = (__bf16*)(ws + HB_OFF);
        __bf16* Kbf = (__bf16*)(ws + KBF_OFF);
        __bf16* Vtg = (__bf16*)(ws + VTG_OFF);
        p01_state<<<dim3(256),   dim3(256), 0, stream>>>(K, V, Kbf, Vtg, G);
        p2_prefix<<<dim3(10240), dim3(256), 0, stream>>>(G, Hb);
        p3_attend<<<dim3(4096),  dim3(64),  0, stream>>>(Q, Kbf, Vtg, Hb, O);
    } else {
        taylor_mono<<<dim3(512), dim3(128), 0, stream>>>(Q, K, V, O);
    }
}

// Round 4
// 54.641 us; speedup vs baseline: 1.1162x; 1.1162x over previous
//
#include <hip/hip_runtime.h>

// Causal quadratic linear attention, chunked-scan formulation.
//   (q.k)^2 = sum_{i,j} q_i q_j k_i k_j   (256 ordered-pair features, F = 16i+j)
// Phases: p01 (fused convert + per-chunk state G, e-split over 2 blocks),
//         p2  (parallel exclusive chunk prefix -> Hb, XCD-pinned by head),
//         p3  (state apply + intra-chunk causal; 16q x 80e per wave, 2-deep
//              K/V software pipeline, no duplicated MFMA work).

#define SEQN 4096
#define NHEAD 8
#define DKEY 16
#define DVAL 64
#define CHUNK 256
#define NCHUNK 16
#define ALPHA 0.03125f
#define VT2S 264    // bf16 row stride (16B-aligned)
#define KTFS 268    // f32 row stride

typedef float f32x4 __attribute__((ext_vector_type(4)));
typedef __bf16 bf16x8 __attribute__((ext_vector_type(8)));
typedef __bf16 bf16x2 __attribute__((ext_vector_type(2)));
typedef unsigned long long u64;
typedef u64 u64x2 __attribute__((ext_vector_type(2)));

__device__ inline float bf2f(__bf16 x) {
    unsigned short u = __builtin_bit_cast(unsigned short, x);
    unsigned int v = ((unsigned int)u) << 16;
    return __builtin_bit_cast(float, v);
}

// ---------------- Phase 01: convert K/V + per-chunk state G^T[e][f] ----------------
// grid: (h, c, eh2) = 256 blocks x 256 thr; h = bid&7 pins head -> XCD.
__global__ __launch_bounds__(256, 1)
void p01_state(const float* __restrict__ Kg, const float* __restrict__ Vg,
               __bf16* __restrict__ Kbf, __bf16* __restrict__ Vtg,
               __bf16* __restrict__ G)
{
    __shared__ __align__(16) __bf16 Vt2[48 * VT2S];
    __shared__ __align__(16) float  Ktf[16 * KTFS];
    const int tid = threadIdx.x;
    const int w = tid >> 6;
    const int lane = tid & 63;
    const int r = lane & 15, g = lane >> 4;
    const int bid = blockIdx.x;
    const int h = bid & 7, c = (bid >> 3) & 15, eh2 = bid >> 7;
    const int k0 = c * CHUNK;
    const int net = eh2 ? 3 : 2;

    // ---- stage K transposed (16 dims x 256 t) + Kbf (eh2==0 only) ----
    {
        const int t = tid;
        const float* kp = Kg + ((size_t)h * SEQN + k0 + t) * DKEY;
        f32x4 kv[4];
        #pragma unroll
        for (int m = 0; m < 4; ++m) kv[m] = *(const f32x4*)(kp + 4 * m);
        #pragma unroll
        for (int m = 0; m < 4; ++m)
            #pragma unroll
            for (int j = 0; j < 4; ++j)
                Ktf[(4 * m + j) * KTFS + t] = kv[m][j];
        if (eh2 == 0) {
            bf16x8 o0, o1;
            #pragma unroll
            for (int j = 0; j < 4; ++j) {
                o0[j] = (__bf16)kv[0][j]; o0[4 + j] = (__bf16)kv[1][j];
                o1[j] = (__bf16)kv[2][j]; o1[4 + j] = (__bf16)kv[3][j];
            }
            __bf16* ko = Kbf + ((size_t)h * SEQN + k0 + t) * DKEY;
            *(bf16x8*)ko = o0;
            *(bf16x8*)(ko + 8) = o1;
        }
    }
    // ---- stage V rows (32 dims per half) ----
    {
        const int el = tid & 31;
        const int seg = tid >> 5;
        const int dim = 32 * eh2 + el;
        const float* __restrict__ Vh = Vg + (size_t)h * SEQN * DVAL;
        #pragma unroll
        for (int p = 0; p < 4; ++p) {
            const int tb = 8 * (seg + 8 * p);
            bf16x8 v;
            #pragma unroll
            for (int j = 0; j < 8; ++j)
                v[j] = (__bf16)Vh[(size_t)(k0 + tb + j) * DVAL + dim];
            *(bf16x8*)&Vt2[el * VT2S + tb] = v;
        }
    }
    if (eh2 == 1) {
        Vt2[32 * VT2S + tid] = (__bf16)1.0f;
        #pragma unroll
        for (int rr = 33; rr < 48; ++rr) Vt2[rr * VT2S + tid] = (__bf16)0.0f;
    }
    __syncthreads();

    // ---- Vtg write-out: permuted V^T rows (static u64-granular permutation) ----
    {
        const int kt_l = tid >> 6;
        const int dloc = tid & 63;
        if (dloc < 32) {
            u64 tmp[16];
            #pragma unroll
            for (int s = 0; s < 16; ++s)
                tmp[s] = *(const u64*)&Vt2[dloc * VT2S + kt_l * 64 + 4 * s];
            u64 o[16];
            #pragma unroll
            for (int hi = 0; hi < 2; ++hi)
                #pragma unroll
                for (int uk = 0; uk < 2; ++uk)
                    #pragma unroll
                    for (int gp = 0; gp < 4; ++gp)
                        o[hi * 8 + 2 * gp + uk] = tmp[hi * 8 + 4 * uk + gp];
            __bf16* vo = Vtg + ((size_t)((h * 64 + c * 4 + kt_l) * 64 + 32 * eh2 + dloc)) * 64;
            #pragma unroll
            for (int m = 0; m < 8; ++m) {
                u64x2 pp; pp[0] = o[2 * m]; pp[1] = o[2 * m + 1];
                *(u64x2*)((u64*)vo + 2 * m) = pp;
            }
        }
    }

    // ---- MFMA: G^T[e][f] = V'^T x Phi ----
    f32x4 acc[4][3] = {};
    #pragma unroll
    for (int ks = 0; ks < 8; ++ks) {
        const int t0 = 32 * ks + 8 * g;
        bf16x8 af[3];
        #pragma unroll
        for (int etl = 0; etl < 3; ++etl)
            if (etl < net)
                af[etl] = *(const bf16x8*)&Vt2[(16 * etl + r) * VT2S + t0];
        const f32x4 kra = *(const f32x4*)&Ktf[r * KTFS + t0];
        const f32x4 krb = *(const f32x4*)&Ktf[r * KTFS + t0 + 4];
        #pragma unroll
        for (int ftl = 0; ftl < 4; ++ftl) {
            const int ft = 4 * w + ftl;
            const f32x4 kfa = *(const f32x4*)&Ktf[ft * KTFS + t0];
            const f32x4 kfb = *(const f32x4*)&Ktf[ft * KTFS + t0 + 4];
            bf16x8 bfrag;
            #pragma unroll
            for (int j = 0; j < 4; ++j) {
                bfrag[j]     = (__bf16)(kfa[j] * kra[j]);
                bfrag[4 + j] = (__bf16)(kfb[j] * krb[j]);
            }
            #pragma unroll
            for (int etl = 0; etl < 3; ++etl)
                if (etl < net)
                    acc[ftl][etl] = __builtin_amdgcn_mfma_f32_16x16x32_bf16(
                        af[etl], bfrag, acc[ftl][etl], 0, 0, 0);
        }
    }
    __bf16* Gc = G + (size_t)((h * NCHUNK + c) * 80) * 256;
    #pragma unroll
    for (int ftl = 0; ftl < 4; ++ftl) {
        const int f = 16 * (4 * w + ftl) + r;
        #pragma unroll
        for (int etl = 0; etl < 3; ++etl)
            if (etl < net) {
                #pragma unroll
                for (int i = 0; i < 4; ++i) {
                    const int e = 32 * eh2 + 16 * etl + 4 * g + i;
                    Gc[e * 256 + f] = (__bf16)acc[ftl][etl][i];
                }
            }
    }
}

// ---------------- Phase 2: parallel exclusive chunk prefix (XCD-pinned) ----------------
// grid: 10240 blocks x 256 thr; h = bid&7 -> same XCD that wrote G[h].
__global__ void p2_prefix(const __bf16* __restrict__ G, __bf16* __restrict__ Hb)
{
    const int h = blockIdx.x & 7;
    const int x = blockIdx.x >> 3;     // 0..1279
    const int c = x & 15;
    const int fb = x >> 4;             // 0..79
    const int fid = fb * 256 + threadIdx.x;
    float acc = 0.f;
    for (int cc = 0; cc < c; ++cc)
        acc += bf2f(G[(size_t)(h * NCHUNK + cc) * 20480 + fid]);
    Hb[(size_t)(h * NCHUNK + c) * 20480 + fid] = (__bf16)acc;
}

// ---------------- Phase 3: state apply + intra-chunk causal ----------------
// grid: (h, qs) = 8*256 = 2048 blocks x 64 thr. Wave: 16 queries x (64d + Z).
// 2-deep software pipeline on intra K/V tiles; first tile prefetched before
// the state-apply loop so state MFMAs hide its latency.

#define LOADKV(KT, KF, VF)                                                        \
    {                                                                             \
        const __bf16* Kb_ = Kbf + ((size_t)h * SEQN + (KT) * 64) * DKEY;          \
        const __bf16* Vb_ = Vtg + (size_t)((h * 64 + (KT)) * 64) * 64;            \
        _Pragma("unroll")                                                         \
        for (int ks_ = 0; ks_ < 2; ++ks_) {                                       \
            _Pragma("unroll")                                                     \
            for (int uk_ = 0; uk_ < 2; ++uk_) {                                   \
                bf16x8 f_ = {};                                                   \
                if (g < 2)                                                        \
                    f_ = *(const bf16x8*)&Kb_[(32 * ks_ + 16 * uk_ + r) * DKEY + 8 * g]; \
                KF[ks_][uk_] = f_;                                                \
            }                                                                     \
            _Pragma("unroll")                                                     \
            for (int dt_ = 0; dt_ < 4; ++dt_)                                     \
                VF[ks_][dt_] = *(const bf16x8*)&Vb_[(size_t)(16 * dt_ + r) * 64 + 32 * ks_ + 8 * g]; \
        }                                                                         \
    }

__global__ __launch_bounds__(64, 2)
void p3_attend(const float* __restrict__ Qg, const __bf16* __restrict__ Kbf,
               const __bf16* __restrict__ Vtg, const __bf16* __restrict__ Hb,
               float* __restrict__ Og)
{
    const int lane = threadIdx.x;
    const int r = lane & 15, g = lane >> 4;
    const int bid = blockIdx.x;
    const int h = bid & 7;
    const int qs = bid >> 3;         // 0..255
    const int qb = qs * 16;
    const int c = qs >> 4;

    // q row (fp32)
    float qr[16];
    {
        const float* qp = Qg + ((size_t)h * SEQN + qb + r) * DKEY;
        #pragma unroll
        for (int m = 0; m < 4; ++m) {
            const f32x4 v = *(const f32x4*)(qp + 4 * m);
            qr[4 * m + 0] = v[0]; qr[4 * m + 1] = v[1];
            qr[4 * m + 2] = v[2]; qr[4 * m + 3] = v[3];
        }
    }
    float qsel[8];
    #pragma unroll
    for (int j = 0; j < 8; ++j) qsel[j] = (g & 1) ? qr[8 + j] : qr[j];
    bf16x8 qfrag = {};
    if (g < 2) {
        #pragma unroll
        for (int j = 0; j < 8; ++j) qfrag[j] = (__bf16)qsel[j];
    }

    const int ktlo = 4 * c;
    const int ktmax = qs >> 2;

    // prefetch first intra K/V tile (latency hidden under state apply)
    bf16x8 kfA[2][2], vfA[2][4], kfB[2][2], vfB[2][4];
    LOADKV(ktlo, kfA, vfA);

    f32x4 oacc[4] = {};
    f32x4 zacc4 = {};
    float zin = 0.f;

    // ---- state apply: O += Psi(q) x H_{<c} ----
    if (c > 0) {
        const __bf16* Hc = Hb + (size_t)((h * NCHUNK + c) * 80) * 256;
        #pragma unroll
        for (int ks = 0; ks < 8; ++ks) {
            const int t0 = 32 * ks + 8 * g;
            bf16x8 af[4];
            #pragma unroll
            for (int dt = 0; dt < 4; ++dt)
                af[dt] = *(const bf16x8*)&Hc[(16 * dt + r) * 256 + t0];
            const bf16x8 afz = *(const bf16x8*)&Hc[(64 + r) * 256 + t0];
            const float qi = ALPHA * ((g & 2) ? qr[2 * ks + 1] : qr[2 * ks]);
            bf16x8 pf;
            #pragma unroll
            for (int j = 0; j < 8; ++j) pf[j] = (__bf16)(qi * qsel[j]);
            #pragma unroll
            for (int dt = 0; dt < 4; ++dt)
                oacc[dt] = __builtin_amdgcn_mfma_f32_16x16x32_bf16(af[dt], pf, oacc[dt], 0, 0, 0);
            zacc4 = __builtin_amdgcn_mfma_f32_16x16x32_bf16(afz, pf, zacc4, 0, 0, 0);
        }
    }

    // ---- intra-chunk causal tiles (2-deep pipeline) ----
    const int qG = qb + r;
    for (int kt = ktlo; kt <= ktmax; ++kt) {
        const bool last = (kt == ktmax);
        if (!last) LOADKV(kt + 1, kfB, vfB);

        const int k0 = kt * 64;
        const bool diag = last;
        #pragma unroll
        for (int ks = 0; ks < 2; ++ks) {
            const f32x4 zero4 = {};
            f32x4 s[2];
            #pragma unroll
            for (int uk = 0; uk < 2; ++uk)
                s[uk] = __builtin_amdgcn_mfma_f32_16x16x32_bf16(
                    kfA[ks][uk], qfrag, zero4, 0, 0, 0);
            bf16x8 pf;
            float zs = 0.f;
            #pragma unroll
            for (int uk = 0; uk < 2; ++uk) {
                const int kGb = k0 + 32 * ks + 16 * uk + 4 * g;
                #pragma unroll
                for (int i = 0; i < 4; ++i) {
                    const float sv = s[uk][i];
                    float p = ALPHA * sv * sv;
                    if (diag && (kGb + i > qG)) p = 0.f;
                    zs += p;
                    pf[4 * uk + i] = (__bf16)p;
                }
            }
            zin += zs;
            #pragma unroll
            for (int dt = 0; dt < 4; ++dt)
                oacc[dt] = __builtin_amdgcn_mfma_f32_16x16x32_bf16(
                    vfA[ks][dt], pf, oacc[dt], 0, 0, 0);
        }

        if (!last) {
            #pragma unroll
            for (int ks = 0; ks < 2; ++ks) {
                #pragma unroll
                for (int uk = 0; uk < 2; ++uk) kfA[ks][uk] = kfB[ks][uk];
                #pragma unroll
                for (int dt = 0; dt < 4; ++dt) vfA[ks][dt] = vfB[ks][dt];
            }
        }
    }

    // ---- stores ----
    const int q = qb + r;
    #pragma unroll
    for (int dt = 0; dt < 4; ++dt) {
        float* op = Og + ((size_t)h * SEQN + q) * DVAL + 16 * dt + 4 * g;
        *(f32x4*)op = oacc[dt];
    }
    zin += __shfl_xor(zin, 16); zin += __shfl_xor(zin, 32);
    if (lane < 16) {   // g==0 lanes: zacc4[0] holds the e=64 (ones) row for query r
        float* zp = Og + (size_t)NHEAD * SEQN * DVAL + (size_t)h * SEQN + qb;
        zp[r] = zin + zacc4[0];
    }
}

// ---------------- Fallback (monolithic) if workspace too small ----------------
__global__ __launch_bounds__(128, 2)
void taylor_mono(const float* __restrict__ Qg, const float* __restrict__ Kg,
                 const float* __restrict__ Vg, float* __restrict__ Og)
{
    __shared__ __align__(16) __bf16 Kl[64 * 32];
    __shared__ __align__(16) __bf16 Vt[64 * 72];
    const int tid = threadIdx.x;
    const int wv = tid >> 6;
    const int lane = tid & 63;
    const int r = lane & 15, g = lane >> 4;
    const int bid = blockIdx.x;
    const int h = bid & 7;
    const int tt = bid >> 3;
    const int qt = (tt & 1) ? (tt >> 1) : (63 - (tt >> 1));
    const int qb = qt * 64 + wv * 32;
    const float* __restrict__ Qh = Qg + (size_t)h * SEQN * DKEY;
    const float* __restrict__ Kh = Kg + (size_t)h * SEQN * DKEY;
    const float* __restrict__ Vh = Vg + (size_t)h * SEQN * DVAL;
    for (int row = tid; row < 64; row += 128) {
        bf16x8 z = {};
        *(bf16x8*)&Kl[row * 32 + 16] = z;
        *(bf16x8*)&Kl[row * 32 + 24] = z;
    }
    bf16x8 qfrag[2];
    #pragma unroll
    for (int uq = 0; uq < 2; ++uq) {
        bf16x8 f = {};
        if (g < 2) {
            const float* qp = Qh + (size_t)(qb + 16 * uq + r) * DKEY + 8 * g;
            const f32x4 a = *(const f32x4*)qp;
            const f32x4 b = *(const f32x4*)(qp + 4);
            #pragma unroll
            for (int j = 0; j < 4; ++j) { f[j] = (__bf16)a[j]; f[4 + j] = (__bf16)b[j]; }
        }
        qfrag[uq] = f;
    }
    f32x4 oacc[2][4] = {};
    float zacc0 = 0.f, zacc1 = 0.f;
    const int nkt = qt + 1;
    for (int kt = 0; kt < nkt; ++kt) {
        const int k0 = kt * 64;
        {
            const int key = tid >> 1, half = tid & 1;
            const float* kp = Kh + (size_t)(k0 + key) * DKEY + 8 * half;
            const f32x4 a = *(const f32x4*)kp;
            const f32x4 b = *(const f32x4*)(kp + 4);
            bf16x8 kb;
            #pragma unroll
            for (int j = 0; j < 4; ++j) { kb[j] = (__bf16)a[j]; kb[4 + j] = (__bf16)b[j]; }
            *(bf16x8*)&Kl[key * 32 + 8 * half] = kb;
        }
        {
            const int d = tid & 63;
            const int kp2 = (tid >> 6) * 2;
            #pragma unroll
            for (int i = 0; i < 16; ++i) {
                const int kk = i * 4 + kp2;
                const float a0 = Vh[(size_t)(k0 + kk) * DVAL + d];
                const float a1 = Vh[(size_t)(k0 + kk + 1) * DVAL + d];
                const int w32 = kk & 31;
                const int col = (kk & 32) + ((w32 >> 2) & 3) * 8 + ((w32 >> 4) << 2) + (kk & 3);
                bf16x2 p; p[0] = (__bf16)a0; p[1] = (__bf16)a1;
                *(bf16x2*)&Vt[d * 72 + col] = p;
            }
        }
        __syncthreads();
        const bool diag = (kt + 1 == nkt);
        #pragma unroll
        for (int ks = 0; ks < 2; ++ks) {
            if (k0 + 32 * ks < qb + 32) {
                bf16x8 vfrag[4];
                #pragma unroll
                for (int dt = 0; dt < 4; ++dt)
                    vfrag[dt] = *(const bf16x8*)&Vt[(16 * dt + r) * 72 + 32 * ks + 8 * g];
                bf16x8 kf[2];
                #pragma unroll
                for (int uk = 0; uk < 2; ++uk)
                    kf[uk] = *(const bf16x8*)&Kl[(32 * ks + 16 * uk + r) * 32 + 8 * g];
                const f32x4 zero4 = {};
                f32x4 s[2][2];
                #pragma unroll
                for (int uq = 0; uq < 2; ++uq)
                    #pragma unroll
                    for (int uk = 0; uk < 2; ++uk)
                        s[uq][uk] = __builtin_amdgcn_mfma_f32_16x16x32_bf16(
                            kf[uk], qfrag[uq], zero4, 0, 0, 0);
                #pragma unroll
                for (int uq = 0; uq < 2; ++uq) {
                    bf16x8 pf;
                    float zs = 0.f;
                    #pragma unroll
                    for (int uk = 0; uk < 2; ++uk) {
                        const int kGb = k0 + 32 * ks + 16 * uk + 4 * g;
                        const int qG = qb + 16 * uq + r;
                        #pragma unroll
                        for (int i = 0; i < 4; ++i) {
                            const float sv = s[uq][uk][i];
                            float p = 0.03125f * sv * sv;
                            if (diag && (kGb + i > qG)) p = 0.f;
                            zs += p;
                            pf[4 * uk + i] = (__bf16)p;
                        }
                    }
                    if (uq == 0) zacc0 += zs; else zacc1 += zs;
                    #pragma unroll
                    for (int dt = 0; dt < 4; ++dt)
                        oacc[uq][dt] = __builtin_amdgcn_mfma_f32_16x16x32_bf16(
                            vfrag[dt], pf, oacc[uq][dt], 0, 0, 0);
                }
            }
        }
        __syncthreads();
    }
    #pragma unroll
    for (int uq = 0; uq < 2; ++uq) {
        const int q = qb + 16 * uq + r;
        #pragma unroll
        for (int dt = 0; dt < 4; ++dt) {
            float* op = Og + ((size_t)h * SEQN + q) * DVAL + 16 * dt + 4 * g;
            *(f32x4*)op = oacc[uq][dt];
        }
    }
    zacc0 += __shfl_xor(zacc0, 16); zacc0 += __shfl_xor(zacc0, 32);
    zacc1 += __shfl_xor(zacc1, 16); zacc1 += __shfl_xor(zacc1, 32);
    if (lane < 16) {
        float* zp = Og + (size_t)NHEAD * SEQN * DVAL + (size_t)h * SEQN + qb;
        zp[r] = zacc0;
        zp[16 + r] = zacc1;
    }
}

extern "C" void kernel_launch(void* const* d_in, const int* in_sizes, int n_in,
                              void* d_out, int out_size, void* d_ws, size_t ws_size,
                              hipStream_t stream) {
    const float* Q = (const float*)d_in[0];
    const float* K = (const float*)d_in[1];
    const float* V = (const float*)d_in[2];
    float* O = (float*)d_out;

    const size_t G_OFF   = 0;                      // 8*16*80*256 bf16 = 5,242,880 B
    const size_t HB_OFF  = 5242880;
    const size_t KBF_OFF = 10485760;               // 8*4096*16 bf16 = 1,048,576 B
    const size_t VTG_OFF = 11534336;               // 8*64*64*64 bf16 = 4,194,304 B
    const size_t NEED    = 15728640;

    if (ws_size >= NEED) {
        char* ws = (char*)d_ws;
        __bf16* G   = (__bf16*)(ws + G_OFF);
        __bf16* Hb  = (__bf16*)(ws + HB_OFF);
        __bf16* Kbf = (__bf16*)(ws + KBF_OFF);
        __bf16* Vtg = (__bf16*)(ws + VTG_OFF);
        p01_state<<<dim3(256),   dim3(256), 0, stream>>>(K, V, Kbf, Vtg, G);
        p2_prefix<<<dim3(10240), dim3(256), 0, stream>>>(G, Hb);
        p3_attend<<<dim3(2048),  dim3(64),  0, stream>>>(Q, Kbf, Vtg, Hb, O);
    } else {
        taylor_mono<<<dim3(512), dim3(128), 0, stream>>>(Q, K, V, O);
    }
}

// Round 5
// 44.083 us; speedup vs baseline: 1.3836x; 1.2395x over previous
//
#include <hip/hip_runtime.h>

// Causal quadratic linear attention, chunked-scan formulation.
//   (q.k)^2 = sum_{i,j} q_i q_j k_i k_j   (256 ordered-pair features, f = 16i+j)
// CHUNK=128, NCHUNK=32.
// p01: convert K/V -> bf16 (Kbf, permuted-transposed Vtg) + per-chunk state
//      G^T[80][256] via MFMA. 256 blocks (h,c), inputs read exactly once.
// p2 : fully-parallel exclusive chunk prefix G -> Hb (XCD-pinned by head).
// p3 : per (h,c) block: stage Hb[h][c] (40KB) into LDS once; 8 waves apply
//      state (16q x 64d+Z each) + intra-chunk causal tiles (<=2, pipelined).

#define SEQN 4096
#define NHEAD 8
#define DKEY 16
#define DVAL 64
#define CHUNK 128
#define NCHUNK 32
#define ALPHA 0.03125f
#define VT2S 136    // p01 bf16 row stride (128 cols + pad)
#define KTFS 132    // p01 f32 row stride
#define HCS  264    // p3 LDS bf16 row stride (256 cols + pad, 2-way-free)

typedef float f32x4 __attribute__((ext_vector_type(4)));
typedef __bf16 bf16x4 __attribute__((ext_vector_type(4)));
typedef __bf16 bf16x8 __attribute__((ext_vector_type(8)));
typedef unsigned long long u64;
typedef u64 u64x2 __attribute__((ext_vector_type(2)));

__device__ inline float bf2f(__bf16 x) {
    unsigned short u = __builtin_bit_cast(unsigned short, x);
    unsigned int v = ((unsigned int)u) << 16;
    return __builtin_bit_cast(float, v);
}

// ---------------- Phase 01: convert + per-chunk state ----------------
// grid 256 = (h = bid&7, c = bid>>3), 256 thr (4 waves).
__global__ __launch_bounds__(256, 1)
void p01_state(const float* __restrict__ Kg, const float* __restrict__ Vg,
               __bf16* __restrict__ Kbf, __bf16* __restrict__ Vtg,
               __bf16* __restrict__ G)
{
    __shared__ __align__(16) __bf16 Vt2[80 * VT2S];   // rows: 64 V dims, 64=ones, pad
    __shared__ __align__(16) float  Ktf[16 * KTFS];   // K transposed (dim x t)
    const int tid = threadIdx.x;
    const int w = tid >> 6;
    const int lane = tid & 63;
    const int r = lane & 15, g = lane >> 4;
    const int bid = blockIdx.x;
    const int h = bid & 7, c = bid >> 3;              // c: 0..31
    const int k0 = c * CHUNK;

    // ---- stage K transposed + write Kbf (each key handled by 2 threads) ----
    {
        const int key = tid >> 1, half = tid & 1;
        const float* kp = Kg + ((size_t)h * SEQN + k0 + key) * DKEY + 8 * half;
        const f32x4 a = *(const f32x4*)kp;
        const f32x4 b = *(const f32x4*)(kp + 4);
        #pragma unroll
        for (int j = 0; j < 4; ++j) {
            Ktf[(8 * half + j) * KTFS + key] = a[j];
            Ktf[(8 * half + 4 + j) * KTFS + key] = b[j];
        }
        bf16x8 o;
        #pragma unroll
        for (int j = 0; j < 4; ++j) { o[j] = (__bf16)a[j]; o[4 + j] = (__bf16)b[j]; }
        *(bf16x8*)&Kbf[((size_t)h * SEQN + k0 + key) * DKEY + 8 * half] = o;
    }
    // ---- stage V rows 0..63 (dim el, cols t) ----
    {
        const int el = tid & 63;
        const int seg = tid >> 6;     // 0..3
        const float* __restrict__ Vh = Vg + (size_t)h * SEQN * DVAL;
        #pragma unroll
        for (int p = 0; p < 4; ++p) {
            const int tb = 8 * (seg + 4 * p);    // 0..120
            bf16x8 v;
            #pragma unroll
            for (int j = 0; j < 8; ++j)
                v[j] = (__bf16)Vh[(size_t)(k0 + tb + j) * DVAL + el];
            *(bf16x8*)&Vt2[el * VT2S + tb] = v;
        }
    }
    // ---- rows 64..79: ones row (t<128) then zeros ----
    for (int idx = tid; idx < 16 * VT2S; idx += 256) {
        const int row = idx / VT2S, t = idx - row * VT2S;
        Vt2[(64 + row) * VT2S + t] = (__bf16)((row == 0 && t < 128) ? 1.0f : 0.0f);
    }
    __syncthreads();

    // ---- Vtg write-out: permuted V^T (static u64-granular permutation) ----
    // 2 kt tiles x 64 rows x 2 col-halves = 256 units, one per thread
    {
        const int dloc = tid & 63;
        const int ktl = (tid >> 6) & 1;
        const int hsel = tid >> 7;
        u64 tmp[8];
        #pragma unroll
        for (int s = 0; s < 8; ++s)
            tmp[s] = *(const u64*)&Vt2[dloc * VT2S + ktl * 64 + hsel * 32 + 4 * s];
        u64 o[8];
        #pragma unroll
        for (int uk = 0; uk < 2; ++uk)
            #pragma unroll
            for (int gp = 0; gp < 4; ++gp)
                o[2 * gp + uk] = tmp[4 * uk + gp];
        __bf16* vo = Vtg + ((size_t)((h * 64 + 2 * c + ktl) * 64 + dloc)) * 64 + hsel * 32;
        #pragma unroll
        for (int m = 0; m < 4; ++m) {
            u64x2 pp; pp[0] = o[2 * m]; pp[1] = o[2 * m + 1];
            *(u64x2*)((u64*)vo + 2 * m) = pp;
        }
    }

    // ---- MFMA: G^T[e][f] = V'^T(80x128) x Phi(128x256) ----
    f32x4 acc[4][5] = {};
    #pragma unroll
    for (int ks = 0; ks < 4; ++ks) {
        const int t0 = 32 * ks + 8 * g;
        bf16x8 af[5];
        #pragma unroll
        for (int et = 0; et < 5; ++et)
            af[et] = *(const bf16x8*)&Vt2[(16 * et + r) * VT2S + t0];
        const f32x4 kra = *(const f32x4*)&Ktf[r * KTFS + t0];
        const f32x4 krb = *(const f32x4*)&Ktf[r * KTFS + t0 + 4];
        #pragma unroll
        for (int ftl = 0; ftl < 4; ++ftl) {
            const int ft = 4 * w + ftl;
            const f32x4 kfa = *(const f32x4*)&Ktf[ft * KTFS + t0];
            const f32x4 kfb = *(const f32x4*)&Ktf[ft * KTFS + t0 + 4];
            bf16x8 bfrag;
            #pragma unroll
            for (int j = 0; j < 4; ++j) {
                bfrag[j]     = (__bf16)(kfa[j] * kra[j]);
                bfrag[4 + j] = (__bf16)(kfb[j] * krb[j]);
            }
            #pragma unroll
            for (int et = 0; et < 5; ++et)
                acc[ftl][et] = __builtin_amdgcn_mfma_f32_16x16x32_bf16(
                    af[et], bfrag, acc[ftl][et], 0, 0, 0);
        }
    }
    // ---- write G[h][c][e][f] ----
    __bf16* Gc = G + (size_t)((h * NCHUNK + c) * 80) * 256;
    #pragma unroll
    for (int ftl = 0; ftl < 4; ++ftl) {
        const int f = 16 * (4 * w + ftl) + r;
        #pragma unroll
        for (int et = 0; et < 5; ++et)
            #pragma unroll
            for (int i = 0; i < 4; ++i)
                Gc[(16 * et + 4 * g + i) * 256 + f] = (__bf16)acc[ftl][et][i];
    }
}

// ---------------- Phase 2: parallel exclusive chunk prefix ----------------
// grid 5120 = (h = bid&7, c, fb20), 256 thr, 4 elems/thread (8B loads).
__global__ void p2_prefix(const __bf16* __restrict__ G, __bf16* __restrict__ Hb)
{
    const int h = blockIdx.x & 7;
    const int x = blockIdx.x >> 3;     // 0..639
    const int c = x & 31;
    const int fb = x >> 5;             // 0..19
    const int fid = fb * 1024 + 4 * threadIdx.x;
    f32x4 acc = {};
    for (int cc = 0; cc < c; ++cc) {
        const bf16x4 v = *(const bf16x4*)&G[(size_t)(h * NCHUNK + cc) * 20480 + fid];
        #pragma unroll
        for (int j = 0; j < 4; ++j) acc[j] += bf2f(v[j]);
    }
    bf16x4 o;
    #pragma unroll
    for (int j = 0; j < 4; ++j) o[j] = (__bf16)acc[j];
    *(bf16x4*)&Hb[(size_t)(h * NCHUNK + c) * 20480 + fid] = o;
}

// ---------------- Phase 3: LDS-staged state apply + intra-chunk causal ----------------
// grid 256 = (h = bid&7, c = bid>>3), 512 thr (8 waves; wave w: queries 16w..16w+15).

#define LOADKV(KT, KF, VF)                                                        \
    {                                                                             \
        const __bf16* Kb_ = Kbf + ((size_t)h * SEQN + (KT) * 64) * DKEY;          \
        const __bf16* Vb_ = Vtg + (size_t)((h * 64 + (KT)) * 64) * 64;            \
        _Pragma("unroll")                                                         \
        for (int ks_ = 0; ks_ < 2; ++ks_) {                                       \
            _Pragma("unroll")                                                     \
            for (int uk_ = 0; uk_ < 2; ++uk_) {                                   \
                bf16x8 f_ = {};                                                   \
                if (g < 2)                                                        \
                    f_ = *(const bf16x8*)&Kb_[(32 * ks_ + 16 * uk_ + r) * DKEY + 8 * g]; \
                KF[ks_][uk_] = f_;                                                \
            }                                                                     \
            _Pragma("unroll")                                                     \
            for (int dt_ = 0; dt_ < 4; ++dt_)                                     \
                VF[ks_][dt_] = *(const bf16x8*)&Vb_[(size_t)(16 * dt_ + r) * 64 + 32 * ks_ + 8 * g]; \
        }                                                                         \
    }

__global__ __launch_bounds__(512, 2)
void p3_attend(const float* __restrict__ Qg, const __bf16* __restrict__ Kbf,
               const __bf16* __restrict__ Vtg, const __bf16* __restrict__ Hb,
               float* __restrict__ Og)
{
    __shared__ __align__(16) __bf16 Hlds[80 * HCS];   // 42240 B
    const int tid = threadIdx.x;
    const int lane = tid & 63;
    const int r = lane & 15, g = lane >> 4;
    const int w = tid >> 6;          // wave 0..7
    const int bid = blockIdx.x;
    const int h = bid & 7;
    const int c = bid >> 3;          // 0..31
    const int qb = c * CHUNK + 16 * w;

    // ---- Q row (fp32) ----
    float qr[16];
    {
        const float* qp = Qg + ((size_t)h * SEQN + qb + r) * DKEY;
        #pragma unroll
        for (int m = 0; m < 4; ++m) {
            const f32x4 v = *(const f32x4*)(qp + 4 * m);
            qr[4 * m + 0] = v[0]; qr[4 * m + 1] = v[1];
            qr[4 * m + 2] = v[2]; qr[4 * m + 3] = v[3];
        }
    }
    float qsel[8];
    #pragma unroll
    for (int j = 0; j < 8; ++j) qsel[j] = (g & 1) ? qr[8 + j] : qr[j];
    bf16x8 qfrag = {};
    if (g < 2) {
        #pragma unroll
        for (int j = 0; j < 8; ++j) qfrag[j] = (__bf16)qsel[j];
    }

    // ---- prefetch intra tile 0; stage Hc into LDS; prefetch tile 1 ----
    const int ntile = 1 + (w >> 2);    // waves 0..3: 1 tile; 4..7: 2 tiles
    bf16x8 kf[2][2][2], vf[2][2][4];
    LOADKV(2 * c, kf[0], vf[0]);

    if (c > 0) {
        const __bf16* Hbc = Hb + (size_t)(h * NCHUNK + c) * 20480;
        #pragma unroll
        for (int k2 = 0; k2 < 5; ++k2) {
            const int fid = 8 * (tid + 512 * k2);
            const int row = fid >> 8, col = fid & 255;
            const u64x2 v = *(const u64x2*)&Hbc[fid];
            *(u64x2*)&Hlds[row * HCS + col] = v;
        }
    }
    if (w >= 4) LOADKV(2 * c + 1, kf[1], vf[1]);

    f32x4 oacc[4] = {};
    f32x4 zacc4 = {};
    float zin = 0.f;

    // ---- state apply from LDS: O += Psi(q) x H_{<c} ----
    if (c > 0) {
        __syncthreads();
        #pragma unroll
        for (int ks = 0; ks < 8; ++ks) {
            const int t0 = 32 * ks + 8 * g;
            bf16x8 af[4];
            #pragma unroll
            for (int dt = 0; dt < 4; ++dt)
                af[dt] = *(const bf16x8*)&Hlds[(16 * dt + r) * HCS + t0];
            const bf16x8 afz = *(const bf16x8*)&Hlds[(64 + r) * HCS + t0];
            const float qi = ALPHA * ((g & 2) ? qr[2 * ks + 1] : qr[2 * ks]);
            bf16x8 pf;
            #pragma unroll
            for (int j = 0; j < 8; ++j) pf[j] = (__bf16)(qi * qsel[j]);
            #pragma unroll
            for (int dt = 0; dt < 4; ++dt)
                oacc[dt] = __builtin_amdgcn_mfma_f32_16x16x32_bf16(af[dt], pf, oacc[dt], 0, 0, 0);
            zacc4 = __builtin_amdgcn_mfma_f32_16x16x32_bf16(afz, pf, zacc4, 0, 0, 0);
        }
    }

    // ---- intra-chunk causal tiles ----
    const int qG = qb + r;
    #pragma unroll
    for (int tl = 0; tl < 2; ++tl) {
        if (tl < ntile) {
            const bool diag = (tl == ntile - 1);
            const int k0g = (2 * c + tl) * 64;
            #pragma unroll
            for (int ks = 0; ks < 2; ++ks) {
                if (64 * tl + 32 * ks <= 16 * w + 15) {   // wave-uniform
                    const f32x4 zero4 = {};
                    f32x4 s[2];
                    #pragma unroll
                    for (int uk = 0; uk < 2; ++uk)
                        s[uk] = __builtin_amdgcn_mfma_f32_16x16x32_bf16(
                            kf[tl][ks][uk], qfrag, zero4, 0, 0, 0);
                    bf16x8 pf;
                    float zs = 0.f;
                    #pragma unroll
                    for (int uk = 0; uk < 2; ++uk) {
                        const int kGb = k0g + 32 * ks + 16 * uk + 4 * g;
                        #pragma unroll
                        for (int i = 0; i < 4; ++i) {
                            const float sv = s[uk][i];
                            float p = ALPHA * sv * sv;
                            if (diag && (kGb + i > qG)) p = 0.f;
                            zs += p;
                            pf[4 * uk + i] = (__bf16)p;
                        }
                    }
                    zin += zs;
                    #pragma unroll
                    for (int dt = 0; dt < 4; ++dt)
                        oacc[dt] = __builtin_amdgcn_mfma_f32_16x16x32_bf16(
                            vf[tl][ks][dt], pf, oacc[dt], 0, 0, 0);
                }
            }
        }
    }

    // ---- stores ----
    const int q = qb + r;
    #pragma unroll
    for (int dt = 0; dt < 4; ++dt) {
        float* op = Og + ((size_t)h * SEQN + q) * DVAL + 16 * dt + 4 * g;
        *(f32x4*)op = oacc[dt];
    }
    zin += __shfl_xor(zin, 16); zin += __shfl_xor(zin, 32);
    if (lane < 16) {   // g==0: zacc4[0] holds the e=64 (ones) row for query r
        float* zp = Og + (size_t)NHEAD * SEQN * DVAL + (size_t)h * SEQN + qb;
        zp[r] = zin + zacc4[0];
    }
}

// ---------------- Fallback (monolithic) if workspace too small ----------------
__global__ __launch_bounds__(128, 2)
void taylor_mono(const float* __restrict__ Qg, const float* __restrict__ Kg,
                 const float* __restrict__ Vg, float* __restrict__ Og)
{
    __shared__ __align__(16) __bf16 Kl[64 * 32];
    __shared__ __align__(16) __bf16 Vt[64 * 72];
    typedef __bf16 bf16x2 __attribute__((ext_vector_type(2)));
    const int tid = threadIdx.x;
    const int wv = tid >> 6;
    const int lane = tid & 63;
    const int r = lane & 15, g = lane >> 4;
    const int bid = blockIdx.x;
    const int h = bid & 7;
    const int tt = bid >> 3;
    const int qt = (tt & 1) ? (tt >> 1) : (63 - (tt >> 1));
    const int qb = qt * 64 + wv * 32;
    const float* __restrict__ Qh = Qg + (size_t)h * SEQN * DKEY;
    const float* __restrict__ Kh = Kg + (size_t)h * SEQN * DKEY;
    const float* __restrict__ Vh = Vg + (size_t)h * SEQN * DVAL;
    for (int row = tid; row < 64; row += 128) {
        bf16x8 z = {};
        *(bf16x8*)&Kl[row * 32 + 16] = z;
        *(bf16x8*)&Kl[row * 32 + 24] = z;
    }
    bf16x8 qfrag[2];
    #pragma unroll
    for (int uq = 0; uq < 2; ++uq) {
        bf16x8 f = {};
        if (g < 2) {
            const float* qp = Qh + (size_t)(qb + 16 * uq + r) * DKEY + 8 * g;
            const f32x4 a = *(const f32x4*)qp;
            const f32x4 b = *(const f32x4*)(qp + 4);
            #pragma unroll
            for (int j = 0; j < 4; ++j) { f[j] = (__bf16)a[j]; f[4 + j] = (__bf16)b[j]; }
        }
        qfrag[uq] = f;
    }
    f32x4 oacc[2][4] = {};
    float zacc0 = 0.f, zacc1 = 0.f;
    const int nkt = qt + 1;
    for (int kt = 0; kt < nkt; ++kt) {
        const int k0 = kt * 64;
        {
            const int key = tid >> 1, half = tid & 1;
            const float* kp = Kh + (size_t)(k0 + key) * DKEY + 8 * half;
            const f32x4 a = *(const f32x4*)kp;
            const f32x4 b = *(const f32x4*)(kp + 4);
            bf16x8 kb;
            #pragma unroll
            for (int j = 0; j < 4; ++j) { kb[j] = (__bf16)a[j]; kb[4 + j] = (__bf16)b[j]; }
            *(bf16x8*)&Kl[key * 32 + 8 * half] = kb;
        }
        {
            const int d = tid & 63;
            const int kp2 = (tid >> 6) * 2;
            #pragma unroll
            for (int i = 0; i < 16; ++i) {
                const int kk = i * 4 + kp2;
                const float a0 = Vh[(size_t)(k0 + kk) * DVAL + d];
                const float a1 = Vh[(size_t)(k0 + kk + 1) * DVAL + d];
                const int w32 = kk & 31;
                const int col = (kk & 32) + ((w32 >> 2) & 3) * 8 + ((w32 >> 4) << 2) + (kk & 3);
                bf16x2 p; p[0] = (__bf16)a0; p[1] = (__bf16)a1;
                *(bf16x2*)&Vt[d * 72 + col] = p;
            }
        }
        __syncthreads();
        const bool diag = (kt + 1 == nkt);
        #pragma unroll
        for (int ks = 0; ks < 2; ++ks) {
            if (k0 + 32 * ks < qb + 32) {
                bf16x8 vfrag[4];
                #pragma unroll
                for (int dt = 0; dt < 4; ++dt)
                    vfrag[dt] = *(const bf16x8*)&Vt[(16 * dt + r) * 72 + 32 * ks + 8 * g];
                bf16x8 kfr[2];
                #pragma unroll
                for (int uk = 0; uk < 2; ++uk)
                    kfr[uk] = *(const bf16x8*)&Kl[(32 * ks + 16 * uk + r) * 32 + 8 * g];
                const f32x4 zero4 = {};
                f32x4 s[2][2];
                #pragma unroll
                for (int uq = 0; uq < 2; ++uq)
                    #pragma unroll
                    for (int uk = 0; uk < 2; ++uk)
                        s[uq][uk] = __builtin_amdgcn_mfma_f32_16x16x32_bf16(
                            kfr[uk], qfrag[uq], zero4, 0, 0, 0);
                #pragma unroll
                for (int uq = 0; uq < 2; ++uq) {
                    bf16x8 pf;
                    float zs = 0.f;
                    #pragma unroll
                    for (int uk = 0; uk < 2; ++uk) {
                        const int kGb = k0 + 32 * ks + 16 * uk + 4 * g;
                        const int qG = qb + 16 * uq + r;
                        #pragma unroll
                        for (int i = 0; i < 4; ++i) {
                            const float sv = s[uq][uk][i];
                            float p = 0.03125f * sv * sv;
                            if (diag && (kGb + i > qG)) p = 0.f;
                            zs += p;
                            pf[4 * uk + i] = (__bf16)p;
                        }
                    }
                    if (uq == 0) zacc0 += zs; else zacc1 += zs;
                    #pragma unroll
                    for (int dt = 0; dt < 4; ++dt)
                        oacc[uq][dt] = __builtin_amdgcn_mfma_f32_16x16x32_bf16(
                            vfrag[dt], pf, oacc[uq][dt], 0, 0, 0);
                }
            }
        }
        __syncthreads();
    }
    #pragma unroll
    for (int uq = 0; uq < 2; ++uq) {
        const int q = qb + 16 * uq + r;
        #pragma unroll
        for (int dt = 0; dt < 4; ++dt) {
            float* op = Og + ((size_t)h * SEQN + q) * DVAL + 16 * dt + 4 * g;
            *(f32x4*)op = oacc[uq][dt];
        }
    }
    zacc0 += __shfl_xor(zacc0, 16); zacc0 += __shfl_xor(zacc0, 32);
    zacc1 += __shfl_xor(zacc1, 16); zacc1 += __shfl_xor(zacc1, 32);
    if (lane < 16) {
        float* zp = Og + (size_t)NHEAD * SEQN * DVAL + (size_t)h * SEQN + qb;
        zp[r] = zacc0;
        zp[16 + r] = zacc1;
    }
}

extern "C" void kernel_launch(void* const* d_in, const int* in_sizes, int n_in,
                              void* d_out, int out_size, void* d_ws, size_t ws_size,
                              hipStream_t stream) {
    const float* Q = (const float*)d_in[0];
    const float* K = (const float*)d_in[1];
    const float* V = (const float*)d_in[2];
    float* O = (float*)d_out;

    const size_t G_OFF   = 0;                      // 8*32*80*256 bf16 = 10,485,760 B
    const size_t HB_OFF  = 10485760;               // same size
    const size_t KBF_OFF = 20971520;               // 8*4096*16 bf16 = 1,048,576 B
    const size_t VTG_OFF = 22020096;               // 8*64*64*64 bf16 = 4,194,304 B
    const size_t NEED    = 26214400;

    if (ws_size >= NEED) {
        char* ws = (char*)d_ws;
        __bf16* G   = (__bf16*)(ws + G_OFF);
        __bf16* Hb  = (__bf16*)(ws + HB_OFF);
        __bf16* Kbf = (__bf16*)(ws + KBF_OFF);
        __bf16* Vtg = (__bf16*)(ws + VTG_OFF);
        p01_state<<<dim3(256),  dim3(256), 0, stream>>>(K, V, Kbf, Vtg, G);
        p2_prefix<<<dim3(5120), dim3(256), 0, stream>>>(G, Hb);
        p3_attend<<<dim3(256),  dim3(512), 0, stream>>>(Q, Kbf, Vtg, Hb, O);
    } else {
        taylor_mono<<<dim3(512), dim3(128), 0, stream>>>(Q, K, V, O);
    }
}

// Round 6
// 39.518 us; speedup vs baseline: 1.5434x; 1.1155x over previous
//
#include <hip/hip_runtime.h>

// Causal quadratic linear attention, chunked-scan formulation.
//   (q.k)^2 = sum_{i,j} q_i q_j k_i k_j   (256 ordered-pair features, f = 16i+j)
// CHUNK=128, NCHUNK=32.
// p01: convert K/V -> bf16 (Kbf, permuted-transposed Vtg) + per-chunk state
//      G^T[80][256] via MFMA. 256 blocks (h,c).
// p2 : fully-parallel exclusive chunk prefix G -> Hb (XCD-pinned, 16B loads).
// p3 : per (h,c,qh) block (512 blocks, 2/CU): stage Hb[h][c] (40KB) into LDS,
//      4 waves apply state (16q x 64d+Z each) + intra causal tiles.
// All LDS tiles: power-of-2 row stride + XOR swizzle (byte ^= (row&7)<<4)
// -> conflict-free ds_read_b128 for MFMA fragments (was 8-way).

#define SEQN 4096
#define NHEAD 8
#define DKEY 16
#define DVAL 64
#define CHUNK 128
#define NCHUNK 32
#define ALPHA 0.03125f

typedef float f32x4 __attribute__((ext_vector_type(4)));
typedef __bf16 bf16x8 __attribute__((ext_vector_type(8)));
typedef unsigned long long u64;
typedef u64 u64x2 __attribute__((ext_vector_type(2)));

// byte-offset swizzles (row-stride 512B / 256B)
#define SW512(row, colb) (((row) << 9) + ((colb) ^ (((row) & 7) << 4)))
#define SW256(row, colb) (((row) << 8) + ((colb) ^ (((row) & 7) << 4)))

__device__ inline float bf2f(__bf16 x) {
    unsigned short u = __builtin_bit_cast(unsigned short, x);
    unsigned int v = ((unsigned int)u) << 16;
    return __builtin_bit_cast(float, v);
}

// ---------------- Phase 01: convert + per-chunk state ----------------
// grid 256 = (h = bid&7, c = bid>>3), 256 thr (4 waves).
__global__ __launch_bounds__(256, 1)
void p01_state(const float* __restrict__ Kg, const float* __restrict__ Vg,
               __bf16* __restrict__ Kbf, __bf16* __restrict__ Vtg,
               __bf16* __restrict__ G)
{
    __shared__ __align__(128) unsigned char Vt2[80 * 256];   // bf16 [80][128], swz
    __shared__ __align__(128) unsigned char Ktf[16 * 512];   // f32  [16][128], swz
    const int tid = threadIdx.x;
    const int w = tid >> 6;
    const int lane = tid & 63;
    const int r = lane & 15, g = lane >> 4;
    const int bid = blockIdx.x;
    const int h = bid & 7, c = bid >> 3;              // c: 0..31
    const int k0 = c * CHUNK;

    // ---- stage K transposed (swz) + write Kbf ----
    {
        const int key = tid >> 1, half = tid & 1;
        const float* kp = Kg + ((size_t)h * SEQN + k0 + key) * DKEY + 8 * half;
        const f32x4 a = *(const f32x4*)kp;
        const f32x4 b = *(const f32x4*)(kp + 4);
        #pragma unroll
        for (int j = 0; j < 4; ++j) {
            *(float*)(Ktf + SW512(8 * half + j,     key * 4)) = a[j];
            *(float*)(Ktf + SW512(8 * half + 4 + j, key * 4)) = b[j];
        }
        bf16x8 o;
        #pragma unroll
        for (int j = 0; j < 4; ++j) { o[j] = (__bf16)a[j]; o[4 + j] = (__bf16)b[j]; }
        *(bf16x8*)&Kbf[((size_t)h * SEQN + k0 + key) * DKEY + 8 * half] = o;
    }
    // ---- stage V rows 0..63 (dim el, cols t, swz) ----
    {
        const int el = tid & 63;
        const int seg = tid >> 6;     // 0..3
        const float* __restrict__ Vh = Vg + (size_t)h * SEQN * DVAL;
        #pragma unroll
        for (int p = 0; p < 4; ++p) {
            const int tb = 8 * (seg + 4 * p);    // 0..120
            bf16x8 v;
            #pragma unroll
            for (int j = 0; j < 8; ++j)
                v[j] = (__bf16)Vh[(size_t)(k0 + tb + j) * DVAL + el];
            *(bf16x8*)(Vt2 + SW256(el, tb * 2)) = v;
        }
    }
    // ---- rows 64..79: ones (row 64) / zeros, u64-granular ----
    {
        #pragma unroll
        for (int u = tid; u < 512; u += 256) {
            const int row = 64 + (u >> 5);
            const int i = u & 31;                // u64 unit within row
            const u64 val = (row == 64) ? 0x3F803F803F803F80ULL : 0ULL;
            *(u64*)(Vt2 + SW256(row, 8 * i)) = val;
        }
    }
    __syncthreads();

    // ---- Vtg write-out: permuted V^T (static u64-granular permutation) ----
    {
        const int dloc = tid & 63;
        const int ktl = (tid >> 6) & 1;
        const int hsel = tid >> 7;
        u64 tmp[8];
        #pragma unroll
        for (int s = 0; s < 8; ++s)
            tmp[s] = *(const u64*)(Vt2 + SW256(dloc, 128 * ktl + 64 * hsel + 8 * s));
        u64 o[8];
        #pragma unroll
        for (int uk = 0; uk < 2; ++uk)
            #pragma unroll
            for (int gp = 0; gp < 4; ++gp)
                o[2 * gp + uk] = tmp[4 * uk + gp];
        __bf16* vo = Vtg + ((size_t)((h * 64 + 2 * c + ktl) * 64 + dloc)) * 64 + hsel * 32;
        #pragma unroll
        for (int m = 0; m < 4; ++m) {
            u64x2 pp; pp[0] = o[2 * m]; pp[1] = o[2 * m + 1];
            *(u64x2*)((u64*)vo + 2 * m) = pp;
        }
    }

    // ---- MFMA: G^T[e][f] = V'^T(80x128) x Phi(128x256) ----
    f32x4 acc[4][5] = {};
    #pragma unroll
    for (int ks = 0; ks < 4; ++ks) {
        const int t0 = 32 * ks + 8 * g;
        bf16x8 af[5];
        #pragma unroll
        for (int et = 0; et < 5; ++et)
            af[et] = *(const bf16x8*)(Vt2 + SW256(16 * et + r, t0 * 2));
        const f32x4 kra = *(const f32x4*)(Ktf + SW512(r, t0 * 4));
        const f32x4 krb = *(const f32x4*)(Ktf + SW512(r, t0 * 4 + 16));
        #pragma unroll
        for (int ftl = 0; ftl < 4; ++ftl) {
            const int ft = 4 * w + ftl;
            const f32x4 kfa = *(const f32x4*)(Ktf + SW512(ft, t0 * 4));
            const f32x4 kfb = *(const f32x4*)(Ktf + SW512(ft, t0 * 4 + 16));
            bf16x8 bfrag;
            #pragma unroll
            for (int j = 0; j < 4; ++j) {
                bfrag[j]     = (__bf16)(kfa[j] * kra[j]);
                bfrag[4 + j] = (__bf16)(kfb[j] * krb[j]);
            }
            #pragma unroll
            for (int et = 0; et < 5; ++et)
                acc[ftl][et] = __builtin_amdgcn_mfma_f32_16x16x32_bf16(
                    af[et], bfrag, acc[ftl][et], 0, 0, 0);
        }
    }
    // ---- write G[h][c][e][f] ----
    __bf16* Gc = G + (size_t)((h * NCHUNK + c) * 80) * 256;
    #pragma unroll
    for (int ftl = 0; ftl < 4; ++ftl) {
        const int f = 16 * (4 * w + ftl) + r;
        #pragma unroll
        for (int et = 0; et < 5; ++et)
            #pragma unroll
            for (int i = 0; i < 4; ++i)
                Gc[(16 * et + 4 * g + i) * 256 + f] = (__bf16)acc[ftl][et][i];
    }
}

// ---------------- Phase 2: parallel exclusive chunk prefix ----------------
// grid 2560 = (h = bid&7, c, fb10), 256 thr, 8 elems/thread (16B loads).
__global__ void p2_prefix(const __bf16* __restrict__ G, __bf16* __restrict__ Hb)
{
    const int h = blockIdx.x & 7;
    const int x = blockIdx.x >> 3;     // 0..319
    const int c = x & 31;
    const int fb = x >> 5;             // 0..9
    const int fid = fb * 2048 + 8 * threadIdx.x;
    float acc[8] = {};
    for (int cc = 0; cc < c; ++cc) {
        const bf16x8 v = *(const bf16x8*)&G[(size_t)(h * NCHUNK + cc) * 20480 + fid];
        #pragma unroll
        for (int j = 0; j < 8; ++j) acc[j] += bf2f(v[j]);
    }
    bf16x8 o;
    #pragma unroll
    for (int j = 0; j < 8; ++j) o[j] = (__bf16)acc[j];
    *(bf16x8*)&Hb[(size_t)(h * NCHUNK + c) * 20480 + fid] = o;
}

// ---------------- Phase 3: LDS-staged state apply + intra-chunk causal ----------------
// grid 512 = (h = bid&7, c, qh), 256 thr (4 waves; wave w: queries qh*64+16w..+15).

#define LOADKV(KT, KF, VF)                                                        \
    {                                                                             \
        const __bf16* Kb_ = Kbf + ((size_t)h * SEQN + (KT) * 64) * DKEY;          \
        const __bf16* Vb_ = Vtg + (size_t)((h * 64 + (KT)) * 64) * 64;            \
        _Pragma("unroll")                                                         \
        for (int ks_ = 0; ks_ < 2; ++ks_) {                                       \
            _Pragma("unroll")                                                     \
            for (int uk_ = 0; uk_ < 2; ++uk_) {                                   \
                bf16x8 f_ = {};                                                   \
                if (g < 2)                                                        \
                    f_ = *(const bf16x8*)&Kb_[(32 * ks_ + 16 * uk_ + r) * DKEY + 8 * g]; \
                KF[ks_][uk_] = f_;                                                \
            }                                                                     \
            _Pragma("unroll")                                                     \
            for (int dt_ = 0; dt_ < 4; ++dt_)                                     \
                VF[ks_][dt_] = *(const bf16x8*)&Vb_[(size_t)(16 * dt_ + r) * 64 + 32 * ks_ + 8 * g]; \
        }                                                                         \
    }

__global__ __launch_bounds__(256, 2)
void p3_attend(const float* __restrict__ Qg, const __bf16* __restrict__ Kbf,
               const __bf16* __restrict__ Vtg, const __bf16* __restrict__ Hb,
               float* __restrict__ Og)
{
    __shared__ __align__(128) unsigned char Hlds[80 * 512];   // bf16 [80][256], swz
    const int tid = threadIdx.x;
    const int lane = tid & 63;
    const int r = lane & 15, g = lane >> 4;
    const int w = tid >> 6;          // wave 0..3
    const int bid = blockIdx.x;
    const int h = bid & 7;
    const int x = bid >> 3;          // 0..63
    const int c = x >> 1;            // 0..31
    const int qh = x & 1;
    const int qb = c * CHUNK + qh * 64 + 16 * w;

    // ---- Q row (fp32) ----
    float qr[16];
    {
        const float* qp = Qg + ((size_t)h * SEQN + qb + r) * DKEY;
        #pragma unroll
        for (int m = 0; m < 4; ++m) {
            const f32x4 v = *(const f32x4*)(qp + 4 * m);
            qr[4 * m + 0] = v[0]; qr[4 * m + 1] = v[1];
            qr[4 * m + 2] = v[2]; qr[4 * m + 3] = v[3];
        }
    }
    float qsel[8];
    #pragma unroll
    for (int j = 0; j < 8; ++j) qsel[j] = (g & 1) ? qr[8 + j] : qr[j];
    bf16x8 qfrag = {};
    if (g < 2) {
        #pragma unroll
        for (int j = 0; j < 8; ++j) qfrag[j] = (__bf16)qsel[j];
    }

    // ---- prefetch intra tile(s); stage Hb[h][c] into LDS (swz) ----
    bf16x8 kf0[2][2], vf0[2][4], kf1[2][2], vf1[2][4];
    LOADKV(2 * c, kf0, vf0);

    if (c > 0) {
        const __bf16* Hbc = Hb + (size_t)(h * NCHUNK + c) * 20480;
        #pragma unroll
        for (int k2 = 0; k2 < 10; ++k2) {
            const int fid = 8 * tid + 2048 * k2;
            const int row = fid >> 8;
            const int colb = (fid & 255) * 2;
            const u64x2 v = *(const u64x2*)&Hbc[fid];
            *(u64x2*)(Hlds + SW512(row, colb)) = v;
        }
    }
    if (qh == 1) LOADKV(2 * c + 1, kf1, vf1);

    f32x4 oacc[4] = {};
    f32x4 zacc4 = {};
    float zin = 0.f;

    // ---- state apply from LDS: O += Psi(q) x H_{<c} ----
    if (c > 0) {
        __syncthreads();
        #pragma unroll
        for (int ks = 0; ks < 8; ++ks) {
            const int t0 = 32 * ks + 8 * g;
            bf16x8 af[4];
            #pragma unroll
            for (int dt = 0; dt < 4; ++dt)
                af[dt] = *(const bf16x8*)(Hlds + SW512(16 * dt + r, t0 * 2));
            const bf16x8 afz = *(const bf16x8*)(Hlds + SW512(64 + r, t0 * 2));
            const float qi = ALPHA * ((g & 2) ? qr[2 * ks + 1] : qr[2 * ks]);
            bf16x8 pf;
            #pragma unroll
            for (int j = 0; j < 8; ++j) pf[j] = (__bf16)(qi * qsel[j]);
            #pragma unroll
            for (int dt = 0; dt < 4; ++dt)
                oacc[dt] = __builtin_amdgcn_mfma_f32_16x16x32_bf16(af[dt], pf, oacc[dt], 0, 0, 0);
            zacc4 = __builtin_amdgcn_mfma_f32_16x16x32_bf16(afz, pf, zacc4, 0, 0, 0);
        }
    }

    // ---- intra-chunk causal tiles ----
    const int qG = qb + r;
    const int qlocmax = qh * 64 + 16 * w + 15;   // wave's max local query
    #pragma unroll
    for (int tl = 0; tl < 2; ++tl) {
        if (tl <= qh) {
            const bool diag = (tl == qh);
            const int k0g = (2 * c + tl) * 64;
            #pragma unroll
            for (int ks = 0; ks < 2; ++ks) {
                if (64 * tl + 32 * ks <= qlocmax) {   // wave-uniform
                    const f32x4 zero4 = {};
                    f32x4 s[2];
                    #pragma unroll
                    for (int uk = 0; uk < 2; ++uk)
                        s[uk] = __builtin_amdgcn_mfma_f32_16x16x32_bf16(
                            (tl == 0) ? kf0[ks][uk] : kf1[ks][uk], qfrag, zero4, 0, 0, 0);
                    bf16x8 pf;
                    float zs = 0.f;
                    #pragma unroll
                    for (int uk = 0; uk < 2; ++uk) {
                        const int kGb = k0g + 32 * ks + 16 * uk + 4 * g;
                        #pragma unroll
                        for (int i = 0; i < 4; ++i) {
                            const float sv = s[uk][i];
                            float p = ALPHA * sv * sv;
                            if (diag && (kGb + i > qG)) p = 0.f;
                            zs += p;
                            pf[4 * uk + i] = (__bf16)p;
                        }
                    }
                    zin += zs;
                    #pragma unroll
                    for (int dt = 0; dt < 4; ++dt)
                        oacc[dt] = __builtin_amdgcn_mfma_f32_16x16x32_bf16(
                            (tl == 0) ? vf0[ks][dt] : vf1[ks][dt], pf, oacc[dt], 0, 0, 0);
                }
            }
        }
    }

    // ---- stores ----
    const int q = qb + r;
    #pragma unroll
    for (int dt = 0; dt < 4; ++dt) {
        float* op = Og + ((size_t)h * SEQN + q) * DVAL + 16 * dt + 4 * g;
        *(f32x4*)op = oacc[dt];
    }
    zin += __shfl_xor(zin, 16); zin += __shfl_xor(zin, 32);
    if (lane < 16) {   // g==0: zacc4[0] holds the e=64 (ones) row for query r
        float* zp = Og + (size_t)NHEAD * SEQN * DVAL + (size_t)h * SEQN + qb;
        zp[r] = zin + zacc4[0];
    }
}

// ---------------- Fallback (monolithic) if workspace too small ----------------
__global__ __launch_bounds__(128, 2)
void taylor_mono(const float* __restrict__ Qg, const float* __restrict__ Kg,
                 const float* __restrict__ Vg, float* __restrict__ Og)
{
    __shared__ __align__(16) __bf16 Kl[64 * 32];
    __shared__ __align__(16) __bf16 Vt[64 * 72];
    typedef __bf16 bf16x2 __attribute__((ext_vector_type(2)));
    const int tid = threadIdx.x;
    const int wv = tid >> 6;
    const int lane = tid & 63;
    const int r = lane & 15, g = lane >> 4;
    const int bid = blockIdx.x;
    const int h = bid & 7;
    const int tt = bid >> 3;
    const int qt = (tt & 1) ? (tt >> 1) : (63 - (tt >> 1));
    const int qb = qt * 64 + wv * 32;
    const float* __restrict__ Qh = Qg + (size_t)h * SEQN * DKEY;
    const float* __restrict__ Kh = Kg + (size_t)h * SEQN * DKEY;
    const float* __restrict__ Vh = Vg + (size_t)h * SEQN * DVAL;
    for (int row = tid; row < 64; row += 128) {
        bf16x8 z = {};
        *(bf16x8*)&Kl[row * 32 + 16] = z;
        *(bf16x8*)&Kl[row * 32 + 24] = z;
    }
    bf16x8 qfrag[2];
    #pragma unroll
    for (int uq = 0; uq < 2; ++uq) {
        bf16x8 f = {};
        if (g < 2) {
            const float* qp = Qh + (size_t)(qb + 16 * uq + r) * DKEY + 8 * g;
            const f32x4 a = *(const f32x4*)qp;
            const f32x4 b = *(const f32x4*)(qp + 4);
            #pragma unroll
            for (int j = 0; j < 4; ++j) { f[j] = (__bf16)a[j]; f[4 + j] = (__bf16)b[j]; }
        }
        qfrag[uq] = f;
    }
    f32x4 oacc[2][4] = {};
    float zacc0 = 0.f, zacc1 = 0.f;
    const int nkt = qt + 1;
    for (int kt = 0; kt < nkt; ++kt) {
        const int k0 = kt * 64;
        {
            const int key = tid >> 1, half = tid & 1;
            const float* kp = Kh + (size_t)(k0 + key) * DKEY + 8 * half;
            const f32x4 a = *(const f32x4*)kp;
            const f32x4 b = *(const f32x4*)(kp + 4);
            bf16x8 kb;
            #pragma unroll
            for (int j = 0; j < 4; ++j) { kb[j] = (__bf16)a[j]; kb[4 + j] = (__bf16)b[j]; }
            *(bf16x8*)&Kl[key * 32 + 8 * half] = kb;
        }
        {
            const int d = tid & 63;
            const int kp2 = (tid >> 6) * 2;
            #pragma unroll
            for (int i = 0; i < 16; ++i) {
                const int kk = i * 4 + kp2;
                const float a0 = Vh[(size_t)(k0 + kk) * DVAL + d];
                const float a1 = Vh[(size_t)(k0 + kk + 1) * DVAL + d];
                const int w32 = kk & 31;
                const int col = (kk & 32) + ((w32 >> 2) & 3) * 8 + ((w32 >> 4) << 2) + (kk & 3);
                bf16x2 p; p[0] = (__bf16)a0; p[1] = (__bf16)a1;
                *(bf16x2*)&Vt[d * 72 + col] = p;
            }
        }
        __syncthreads();
        const bool diag = (kt + 1 == nkt);
        #pragma unroll
        for (int ks = 0; ks < 2; ++ks) {
            if (k0 + 32 * ks < qb + 32) {
                bf16x8 vfrag[4];
                #pragma unroll
                for (int dt = 0; dt < 4; ++dt)
                    vfrag[dt] = *(const bf16x8*)&Vt[(16 * dt + r) * 72 + 32 * ks + 8 * g];
                bf16x8 kfr[2];
                #pragma unroll
                for (int uk = 0; uk < 2; ++uk)
                    kfr[uk] = *(const bf16x8*)&Kl[(32 * ks + 16 * uk + r) * 32 + 8 * g];
                const f32x4 zero4 = {};
                f32x4 s[2][2];
                #pragma unroll
                for (int uq = 0; uq < 2; ++uq)
                    #pragma unroll
                    for (int uk = 0; uk < 2; ++uk)
                        s[uq][uk] = __builtin_amdgcn_mfma_f32_16x16x32_bf16(
                            kfr[uk], qfrag[uq], zero4, 0, 0, 0);
                #pragma unroll
                for (int uq = 0; uq < 2; ++uq) {
                    bf16x8 pf;
                    float zs = 0.f;
                    #pragma unroll
                    for (int uk = 0; uk < 2; ++uk) {
                        const int kGb = k0 + 32 * ks + 16 * uk + 4 * g;
                        const int qG = qb + 16 * uq + r;
                        #pragma unroll
                        for (int i = 0; i < 4; ++i) {
                            const float sv = s[uq][uk][i];
                            float p = 0.03125f * sv * sv;
                            if (diag && (kGb + i > qG)) p = 0.f;
                            zs += p;
                            pf[4 * uk + i] = (__bf16)p;
                        }
                    }
                    if (uq == 0) zacc0 += zs; else zacc1 += zs;
                    #pragma unroll
                    for (int dt = 0; dt < 4; ++dt)
                        oacc[uq][dt] = __builtin_amdgcn_mfma_f32_16x16x32_bf16(
                            vfrag[dt], pf, oacc[uq][dt], 0, 0, 0);
                }
            }
        }
        __syncthreads();
    }
    #pragma unroll
    for (int uq = 0; uq < 2; ++uq) {
        const int q = qb + 16 * uq + r;
        #pragma unroll
        for (int dt = 0; dt < 4; ++dt) {
            float* op = Og + ((size_t)h * SEQN + q) * DVAL + 16 * dt + 4 * g;
            *(f32x4*)op = oacc[uq][dt];
        }
    }
    zacc0 += __shfl_xor(zacc0, 16); zacc0 += __shfl_xor(zacc0, 32);
    zacc1 += __shfl_xor(zacc1, 16); zacc1 += __shfl_xor(zacc1, 32);
    if (lane < 16) {
        float* zp = Og + (size_t)NHEAD * SEQN * DVAL + (size_t)h * SEQN + qb;
        zp[r] = zacc0;
        zp[16 + r] = zacc1;
    }
}

extern "C" void kernel_launch(void* const* d_in, const int* in_sizes, int n_in,
                              void* d_out, int out_size, void* d_ws, size_t ws_size,
                              hipStream_t stream) {
    const float* Q = (const float*)d_in[0];
    const float* K = (const float*)d_in[1];
    const float* V = (const float*)d_in[2];
    float* O = (float*)d_out;

    const size_t G_OFF   = 0;                      // 8*32*80*256 bf16 = 10,485,760 B
    const size_t HB_OFF  = 10485760;               // same size
    const size_t KBF_OFF = 20971520;               // 8*4096*16 bf16 = 1,048,576 B
    const size_t VTG_OFF = 22020096;               // 8*64*64*64 bf16 = 4,194,304 B
    const size_t NEED    = 26214400;

    if (ws_size >= NEED) {
        char* ws = (char*)d_ws;
        __bf16* G   = (__bf16*)(ws + G_OFF);
        __bf16* Hb  = (__bf16*)(ws + HB_OFF);
        __bf16* Kbf = (__bf16*)(ws + KBF_OFF);
        __bf16* Vtg = (__bf16*)(ws + VTG_OFF);
        p01_state<<<dim3(256),  dim3(256), 0, stream>>>(K, V, Kbf, Vtg, G);
        p2_prefix<<<dim3(2560), dim3(256), 0, stream>>>(G, Hb);
        p3_attend<<<dim3(512),  dim3(256), 0, stream>>>(Q, Kbf, Vtg, Hb, O);
    } else {
        taylor_mono<<<dim3(512), dim3(128), 0, stream>>>(Q, K, V, O);
    }
}

// Round 7
// 38.625 us; speedup vs baseline: 1.5791x; 1.0231x over previous
//
#include <hip/hip_runtime.h>

// Causal quadratic linear attention, chunked-scan formulation.
//   (q.k)^2 = sum_{i,j} q_i q_j k_i k_j   (256 ordered-pair features, f = 16i+j)
// CHUNK=128, NCHUNK=32.
// p01: convert K/V -> bf16 (Kbf, permuted-transposed Vtg) + per-chunk state
//      G^T[80][256] via MFMA. 256 blocks x 512 thr (8 waves), operand-swapped
//      MFMA so the G write is 8B-contiguous per lane.
// p2 : fully-parallel exclusive chunk prefix G -> Hb (XCD-pinned, 16B loads).
// p3 : per (h,c,qh) block (512 blocks, 2/CU): stage Hb[h][c] (40KB) into LDS,
//      4 waves apply state (16q x 64d+Z each) + intra causal tiles.
// All LDS tiles: power-of-2 row stride + XOR swizzle (byte ^= (row&7)<<4).

#define SEQN 4096
#define NHEAD 8
#define DKEY 16
#define DVAL 64
#define CHUNK 128
#define NCHUNK 32
#define ALPHA 0.03125f

typedef float f32x4 __attribute__((ext_vector_type(4)));
typedef __bf16 bf16x4 __attribute__((ext_vector_type(4)));
typedef __bf16 bf16x8 __attribute__((ext_vector_type(8)));
typedef unsigned long long u64;
typedef u64 u64x2 __attribute__((ext_vector_type(2)));

// byte-offset swizzles (row-stride 512B / 256B)
#define SW512(row, colb) (((row) << 9) + ((colb) ^ (((row) & 7) << 4)))
#define SW256(row, colb) (((row) << 8) + ((colb) ^ (((row) & 7) << 4)))

__device__ inline float bf2f(__bf16 x) {
    unsigned short u = __builtin_bit_cast(unsigned short, x);
    unsigned int v = ((unsigned int)u) << 16;
    return __builtin_bit_cast(float, v);
}

// ---------------- Phase 01: convert + per-chunk state ----------------
// grid 256 = (h = bid&7, c = bid>>3), 512 thr (8 waves).
__global__ __launch_bounds__(512, 1)
void p01_state(const float* __restrict__ Kg, const float* __restrict__ Vg,
               __bf16* __restrict__ Kbf, __bf16* __restrict__ Vtg,
               __bf16* __restrict__ G)
{
    __shared__ __align__(128) unsigned char Vt2[80 * 256];   // bf16 [80][128], swz
    __shared__ __align__(128) unsigned char Ktf[16 * 512];   // f32  [16][128], swz
    const int tid = threadIdx.x;
    const int w = tid >> 6;          // wave 0..7
    const int lane = tid & 63;
    const int r = lane & 15, g = lane >> 4;
    const int bid = blockIdx.x;
    const int h = bid & 7, c = bid >> 3;              // c: 0..31
    const int k0 = c * CHUNK;

    // ---- stage K transposed (swz) + write Kbf: key = tid>>2, part = tid&3 ----
    {
        const int key = tid >> 2, part = tid & 3;
        const float* kp = Kg + ((size_t)h * SEQN + k0 + key) * DKEY + 4 * part;
        const f32x4 a = *(const f32x4*)kp;
        #pragma unroll
        for (int j = 0; j < 4; ++j)
            *(float*)(Ktf + SW512(4 * part + j, key * 4)) = a[j];
        bf16x4 o;
        #pragma unroll
        for (int j = 0; j < 4; ++j) o[j] = (__bf16)a[j];
        *(bf16x4*)&Kbf[((size_t)h * SEQN + k0 + key) * DKEY + 4 * part] = o;
    }
    // ---- stage V rows 0..63 (dim el, cols t, swz): seg = tid>>6 (0..7) ----
    {
        const int el = tid & 63;
        const int seg = tid >> 6;
        const float* __restrict__ Vh = Vg + (size_t)h * SEQN * DVAL;
        #pragma unroll
        for (int p = 0; p < 2; ++p) {
            const int tb = 8 * (seg + 8 * p);    // 0..120
            bf16x8 v;
            #pragma unroll
            for (int j = 0; j < 8; ++j)
                v[j] = (__bf16)Vh[(size_t)(k0 + tb + j) * DVAL + el];
            *(bf16x8*)(Vt2 + SW256(el, tb * 2)) = v;
        }
    }
    // ---- rows 64..79: ones (row 64) / zeros, one u64 per thread ----
    {
        const int row = 64 + (tid >> 5);
        const int i = tid & 31;
        const u64 val = (row == 64) ? 0x3F803F803F803F80ULL : 0ULL;
        *(u64*)(Vt2 + SW256(row, 8 * i)) = val;
    }
    __syncthreads();

    // ---- Vtg write-out: permuted V^T (static u64-granular permutation) ----
    // 1024 units (dloc, ktl, hsel, m), 2 per thread.
    #pragma unroll
    for (int uu = 0; uu < 2; ++uu) {
        const int unit = 2 * tid + uu;
        const int m = unit & 3;
        const int hsel = (unit >> 2) & 1;
        const int ktl = (unit >> 3) & 1;
        const int dloc = unit >> 4;
        const u64 t0v = *(const u64*)(Vt2 + SW256(dloc, 128 * ktl + 64 * hsel + 8 * m));
        const u64 t1v = *(const u64*)(Vt2 + SW256(dloc, 128 * ktl + 64 * hsel + 8 * m + 32));
        __bf16* vo = Vtg + ((size_t)((h * 64 + 2 * c + ktl) * 64 + dloc)) * 64 + hsel * 32;
        u64x2 pp; pp[0] = t0v; pp[1] = t1v;
        *(u64x2*)((u64*)vo + 2 * m) = pp;
    }

    // ---- MFMA: G[e][f] = sum_t V'[t][e] * phi[f][t]; wave w owns f-tiles 2w,2w+1 ----
    // operand-swapped: A = phi frag, B = V frag -> C rows = f_local (4g+i), cols = e_local (r)
    f32x4 acc[2][5] = {};
    #pragma unroll
    for (int ks = 0; ks < 4; ++ks) {
        const int t0 = 32 * ks + 8 * g;
        bf16x8 af[5];
        #pragma unroll
        for (int et = 0; et < 5; ++et)
            af[et] = *(const bf16x8*)(Vt2 + SW256(16 * et + r, t0 * 2));
        const f32x4 kra = *(const f32x4*)(Ktf + SW512(r, t0 * 4));
        const f32x4 krb = *(const f32x4*)(Ktf + SW512(r, t0 * 4 + 16));
        #pragma unroll
        for (int fa = 0; fa < 2; ++fa) {
            const int ft = 2 * w + fa;
            const f32x4 kfa = *(const f32x4*)(Ktf + SW512(ft, t0 * 4));
            const f32x4 kfb = *(const f32x4*)(Ktf + SW512(ft, t0 * 4 + 16));
            bf16x8 bfrag;
            #pragma unroll
            for (int j = 0; j < 4; ++j) {
                bfrag[j]     = (__bf16)(kfa[j] * kra[j]);
                bfrag[4 + j] = (__bf16)(kfb[j] * krb[j]);
            }
            #pragma unroll
            for (int et = 0; et < 5; ++et)
                acc[fa][et] = __builtin_amdgcn_mfma_f32_16x16x32_bf16(
                    bfrag, af[et], acc[fa][et], 0, 0, 0);
        }
    }
    // ---- write G[h][c][e][f]: lane writes 4 f-contiguous bf16 (8B) per (fa,et) ----
    __bf16* Gc = G + (size_t)((h * NCHUNK + c) * 80) * 256;
    #pragma unroll
    for (int fa = 0; fa < 2; ++fa) {
        const int fb = 16 * (2 * w + fa) + 4 * g;
        #pragma unroll
        for (int et = 0; et < 5; ++et) {
            bf16x4 o;
            #pragma unroll
            for (int i = 0; i < 4; ++i) o[i] = (__bf16)acc[fa][et][i];
            *(bf16x4*)&Gc[(size_t)(16 * et + r) * 256 + fb] = o;
        }
    }
}

// ---------------- Phase 2: parallel exclusive chunk prefix ----------------
// grid 2560 = (h = bid&7, c, fb10), 256 thr, 8 elems/thread (16B loads).
__global__ void p2_prefix(const __bf16* __restrict__ G, __bf16* __restrict__ Hb)
{
    const int h = blockIdx.x & 7;
    const int x = blockIdx.x >> 3;     // 0..319
    const int c = x & 31;
    const int fb = x >> 5;             // 0..9
    const int fid = fb * 2048 + 8 * threadIdx.x;
    float acc[8] = {};
    for (int cc = 0; cc < c; ++cc) {
        const bf16x8 v = *(const bf16x8*)&G[(size_t)(h * NCHUNK + cc) * 20480 + fid];
        #pragma unroll
        for (int j = 0; j < 8; ++j) acc[j] += bf2f(v[j]);
    }
    bf16x8 o;
    #pragma unroll
    for (int j = 0; j < 8; ++j) o[j] = (__bf16)acc[j];
    *(bf16x8*)&Hb[(size_t)(h * NCHUNK + c) * 20480 + fid] = o;
}

// ---------------- Phase 3: LDS-staged state apply + intra-chunk causal ----------------
// grid 512 = (h = bid&7, c, qh), 256 thr (4 waves; wave w: queries qh*64+16w..+15).

#define LOADKV(KT, KF, VF)                                                        \
    {                                                                             \
        const __bf16* Kb_ = Kbf + ((size_t)h * SEQN + (KT) * 64) * DKEY;          \
        const __bf16* Vb_ = Vtg + (size_t)((h * 64 + (KT)) * 64) * 64;            \
        _Pragma("unroll")                                                         \
        for (int ks_ = 0; ks_ < 2; ++ks_) {                                       \
            _Pragma("unroll")                                                     \
            for (int uk_ = 0; uk_ < 2; ++uk_) {                                   \
                bf16x8 f_ = {};                                                   \
                if (g < 2)                                                        \
                    f_ = *(const bf16x8*)&Kb_[(32 * ks_ + 16 * uk_ + r) * DKEY + 8 * g]; \
                KF[ks_][uk_] = f_;                                                \
            }                                                                     \
            _Pragma("unroll")                                                     \
            for (int dt_ = 0; dt_ < 4; ++dt_)                                     \
                VF[ks_][dt_] = *(const bf16x8*)&Vb_[(size_t)(16 * dt_ + r) * 64 + 32 * ks_ + 8 * g]; \
        }                                                                         \
    }

__global__ __launch_bounds__(256, 2)
void p3_attend(const float* __restrict__ Qg, const __bf16* __restrict__ Kbf,
               const __bf16* __restrict__ Vtg, const __bf16* __restrict__ Hb,
               float* __restrict__ Og)
{
    __shared__ __align__(128) unsigned char Hlds[80 * 512];   // bf16 [80][256], swz
    const int tid = threadIdx.x;
    const int lane = tid & 63;
    const int r = lane & 15, g = lane >> 4;
    const int w = tid >> 6;          // wave 0..3
    const int bid = blockIdx.x;
    const int h = bid & 7;
    const int x = bid >> 3;          // 0..63
    const int c = x >> 1;            // 0..31
    const int qh = x & 1;
    const int qb = c * CHUNK + qh * 64 + 16 * w;

    // ---- Q row (fp32) ----
    float qr[16];
    {
        const float* qp = Qg + ((size_t)h * SEQN + qb + r) * DKEY;
        #pragma unroll
        for (int m = 0; m < 4; ++m) {
            const f32x4 v = *(const f32x4*)(qp + 4 * m);
            qr[4 * m + 0] = v[0]; qr[4 * m + 1] = v[1];
            qr[4 * m + 2] = v[2]; qr[4 * m + 3] = v[3];
        }
    }
    float qsel[8];
    #pragma unroll
    for (int j = 0; j < 8; ++j) qsel[j] = (g & 1) ? qr[8 + j] : qr[j];
    bf16x8 qfrag = {};
    if (g < 2) {
        #pragma unroll
        for (int j = 0; j < 8; ++j) qfrag[j] = (__bf16)qsel[j];
    }

    // ---- prefetch intra tile(s); stage Hb[h][c] into LDS (swz) ----
    bf16x8 kf0[2][2], vf0[2][4], kf1[2][2], vf1[2][4];
    LOADKV(2 * c, kf0, vf0);

    if (c > 0) {
        const __bf16* Hbc = Hb + (size_t)(h * NCHUNK + c) * 20480;
        #pragma unroll
        for (int k2 = 0; k2 < 10; ++k2) {
            const int fid = 8 * tid + 2048 * k2;
            const int row = fid >> 8;
            const int colb = (fid & 255) * 2;
            const u64x2 v = *(const u64x2*)&Hbc[fid];
            *(u64x2*)(Hlds + SW512(row, colb)) = v;
        }
    }
    if (qh == 1) LOADKV(2 * c + 1, kf1, vf1);

    f32x4 oacc[4] = {};
    f32x4 zacc4 = {};
    float zin = 0.f;

    // ---- state apply from LDS: O += Psi(q) x H_{<c} ----
    if (c > 0) {
        __syncthreads();
        #pragma unroll
        for (int ks = 0; ks < 8; ++ks) {
            const int t0 = 32 * ks + 8 * g;
            bf16x8 af[4];
            #pragma unroll
            for (int dt = 0; dt < 4; ++dt)
                af[dt] = *(const bf16x8*)(Hlds + SW512(16 * dt + r, t0 * 2));
            const bf16x8 afz = *(const bf16x8*)(Hlds + SW512(64 + r, t0 * 2));
            const float qi = ALPHA * ((g & 2) ? qr[2 * ks + 1] : qr[2 * ks]);
            bf16x8 pf;
            #pragma unroll
            for (int j = 0; j < 8; ++j) pf[j] = (__bf16)(qi * qsel[j]);
            #pragma unroll
            for (int dt = 0; dt < 4; ++dt)
                oacc[dt] = __builtin_amdgcn_mfma_f32_16x16x32_bf16(af[dt], pf, oacc[dt], 0, 0, 0);
            zacc4 = __builtin_amdgcn_mfma_f32_16x16x32_bf16(afz, pf, zacc4, 0, 0, 0);
        }
    }

    // ---- intra-chunk causal tiles ----
    const int qG = qb + r;
    const int qlocmax = qh * 64 + 16 * w + 15;   // wave's max local query
    #pragma unroll
    for (int tl = 0; tl < 2; ++tl) {
        if (tl <= qh) {
            const bool diag = (tl == qh);
            const int k0g = (2 * c + tl) * 64;
            #pragma unroll
            for (int ks = 0; ks < 2; ++ks) {
                if (64 * tl + 32 * ks <= qlocmax) {   // wave-uniform
                    const f32x4 zero4 = {};
                    f32x4 s[2];
                    #pragma unroll
                    for (int uk = 0; uk < 2; ++uk)
                        s[uk] = __builtin_amdgcn_mfma_f32_16x16x32_bf16(
                            (tl == 0) ? kf0[ks][uk] : kf1[ks][uk], qfrag, zero4, 0, 0, 0);
                    bf16x8 pf;
                    float zs = 0.f;
                    #pragma unroll
                    for (int uk = 0; uk < 2; ++uk) {
                        const int kGb = k0g + 32 * ks + 16 * uk + 4 * g;
                        #pragma unroll
                        for (int i = 0; i < 4; ++i) {
                            const float sv = s[uk][i];
                            float p = ALPHA * sv * sv;
                            if (diag && (kGb + i > qG)) p = 0.f;
                            zs += p;
                            pf[4 * uk + i] = (__bf16)p;
                        }
                    }
                    zin += zs;
                    #pragma unroll
                    for (int dt = 0; dt < 4; ++dt)
                        oacc[dt] = __builtin_amdgcn_mfma_f32_16x16x32_bf16(
                            (tl == 0) ? vf0[ks][dt] : vf1[ks][dt], pf, oacc[dt], 0, 0, 0);
                }
            }
        }
    }

    // ---- stores ----
    const int q = qb + r;
    #pragma unroll
    for (int dt = 0; dt < 4; ++dt) {
        float* op = Og + ((size_t)h * SEQN + q) * DVAL + 16 * dt + 4 * g;
        *(f32x4*)op = oacc[dt];
    }
    zin += __shfl_xor(zin, 16); zin += __shfl_xor(zin, 32);
    if (lane < 16) {   // g==0: zacc4[0] holds the e=64 (ones) row for query r
        float* zp = Og + (size_t)NHEAD * SEQN * DVAL + (size_t)h * SEQN + qb;
        zp[r] = zin + zacc4[0];
    }
}

// ---------------- Fallback (monolithic) if workspace too small ----------------
__global__ __launch_bounds__(128, 2)
void taylor_mono(const float* __restrict__ Qg, const float* __restrict__ Kg,
                 const float* __restrict__ Vg, float* __restrict__ Og)
{
    __shared__ __align__(16) __bf16 Kl[64 * 32];
    __shared__ __align__(16) __bf16 Vt[64 * 72];
    typedef __bf16 bf16x2 __attribute__((ext_vector_type(2)));
    const int tid = threadIdx.x;
    const int wv = tid >> 6;
    const int lane = tid & 63;
    const int r = lane & 15, g = lane >> 4;
    const int bid = blockIdx.x;
    const int h = bid & 7;
    const int tt = bid >> 3;
    const int qt = (tt & 1) ? (tt >> 1) : (63 - (tt >> 1));
    const int qb = qt * 64 + wv * 32;
    const float* __restrict__ Qh = Qg + (size_t)h * SEQN * DKEY;
    const float* __restrict__ Kh = Kg + (size_t)h * SEQN * DKEY;
    const float* __restrict__ Vh = Vg + (size_t)h * SEQN * DVAL;
    for (int row = tid; row < 64; row += 128) {
        bf16x8 z = {};
        *(bf16x8*)&Kl[row * 32 + 16] = z;
        *(bf16x8*)&Kl[row * 32 + 24] = z;
    }
    bf16x8 qfrag[2];
    #pragma unroll
    for (int uq = 0; uq < 2; ++uq) {
        bf16x8 f = {};
        if (g < 2) {
            const float* qp = Qh + (size_t)(qb + 16 * uq + r) * DKEY + 8 * g;
            const f32x4 a = *(const f32x4*)qp;
            const f32x4 b = *(const f32x4*)(qp + 4);
            #pragma unroll
            for (int j = 0; j < 4; ++j) { f[j] = (__bf16)a[j]; f[4 + j] = (__bf16)b[j]; }
        }
        qfrag[uq] = f;
    }
    f32x4 oacc[2][4] = {};
    float zacc0 = 0.f, zacc1 = 0.f;
    const int nkt = qt + 1;
    for (int kt = 0; kt < nkt; ++kt) {
        const int k0 = kt * 64;
        {
            const int key = tid >> 1, half = tid & 1;
            const float* kp = Kh + (size_t)(k0 + key) * DKEY + 8 * half;
            const f32x4 a = *(const f32x4*)kp;
            const f32x4 b = *(const f32x4*)(kp + 4);
            bf16x8 kb;
            #pragma unroll
            for (int j = 0; j < 4; ++j) { kb[j] = (__bf16)a[j]; kb[4 + j] = (__bf16)b[j]; }
            *(bf16x8*)&Kl[key * 32 + 8 * half] = kb;
        }
        {
            const int d = tid & 63;
            const int kp2 = (tid >> 6) * 2;
            #pragma unroll
            for (int i = 0; i < 16; ++i) {
                const int kk = i * 4 + kp2;
                const float a0 = Vh[(size_t)(k0 + kk) * DVAL + d];
                const float a1 = Vh[(size_t)(k0 + kk + 1) * DVAL + d];
                const int w32 = kk & 31;
                const int col = (kk & 32) + ((w32 >> 2) & 3) * 8 + ((w32 >> 4) << 2) + (kk & 3);
                bf16x2 p; p[0] = (__bf16)a0; p[1] = (__bf16)a1;
                *(bf16x2*)&Vt[d * 72 + col] = p;
            }
        }
        __syncthreads();
        const bool diag = (kt + 1 == nkt);
        #pragma unroll
        for (int ks = 0; ks < 2; ++ks) {
            if (k0 + 32 * ks < qb + 32) {
                bf16x8 vfrag[4];
                #pragma unroll
                for (int dt = 0; dt < 4; ++dt)
                    vfrag[dt] = *(const bf16x8*)&Vt[(16 * dt + r) * 72 + 32 * ks + 8 * g];
                bf16x8 kfr[2];
                #pragma unroll
                for (int uk = 0; uk < 2; ++uk)
                    kfr[uk] = *(const bf16x8*)&Kl[(32 * ks + 16 * uk + r) * 32 + 8 * g];
                const f32x4 zero4 = {};
                f32x4 s[2][2];
                #pragma unroll
                for (int uq = 0; uq < 2; ++uq)
                    #pragma unroll
                    for (int uk = 0; uk < 2; ++uk)
                        s[uq][uk] = __builtin_amdgcn_mfma_f32_16x16x32_bf16(
                            kfr[uk], qfrag[uq], zero4, 0, 0, 0);
                #pragma unroll
                for (int uq = 0; uq < 2; ++uq) {
                    bf16x8 pf;
                    float zs = 0.f;
                    #pragma unroll
                    for (int uk = 0; uk < 2; ++uk) {
                        const int kGb = k0 + 32 * ks + 16 * uk + 4 * g;
                        const int qG = qb + 16 * uq + r;
                        #pragma unroll
                        for (int i = 0; i < 4; ++i) {
                            const float sv = s[uq][uk][i];
                            float p = 0.03125f * sv * sv;
                            if (diag && (kGb + i > qG)) p = 0.f;
                            zs += p;
                            pf[4 * uk + i] = (__bf16)p;
                        }
                    }
                    if (uq == 0) zacc0 += zs; else zacc1 += zs;
                    #pragma unroll
                    for (int dt = 0; dt < 4; ++dt)
                        oacc[uq][dt] = __builtin_amdgcn_mfma_f32_16x16x32_bf16(
                            vfrag[dt], pf, oacc[uq][dt], 0, 0, 0);
                }
            }
        }
        __syncthreads();
    }
    #pragma unroll
    for (int uq = 0; uq < 2; ++uq) {
        const int q = qb + 16 * uq + r;
        #pragma unroll
        for (int dt = 0; dt < 4; ++dt) {
            float* op = Og + ((size_t)h * SEQN + q) * DVAL + 16 * dt + 4 * g;
            *(f32x4*)op = oacc[uq][dt];
        }
    }
    zacc0 += __shfl_xor(zacc0, 16); zacc0 += __shfl_xor(zacc0, 32);
    zacc1 += __shfl_xor(zacc1, 16); zacc1 += __shfl_xor(zacc1, 32);
    if (lane < 16) {
        float* zp = Og + (size_t)NHEAD * SEQN * DVAL + (size_t)h * SEQN + qb;
        zp[r] = zacc0;
        zp[16 + r] = zacc1;
    }
}

extern "C" void kernel_launch(void* const* d_in, const int* in_sizes, int n_in,
                              void* d_out, int out_size, void* d_ws, size_t ws_size,
                              hipStream_t stream) {
    const float* Q = (const float*)d_in[0];
    const float* K = (const float*)d_in[1];
    const float* V = (const float*)d_in[2];
    float* O = (float*)d_out;

    const size_t G_OFF   = 0;                      // 8*32*80*256 bf16 = 10,485,760 B
    const size_t HB_OFF  = 10485760;               // same size
    const size_t KBF_OFF = 20971520;               // 8*4096*16 bf16 = 1,048,576 B
    const size_t VTG_OFF = 22020096;               // 8*64*64*64 bf16 = 4,194,304 B
    const size_t NEED    = 26214400;

    if (ws_size >= NEED) {
        char* ws = (char*)d_ws;
        __bf16* G   = (__bf16*)(ws + G_OFF);
        __bf16* Hb  = (__bf16*)(ws + HB_OFF);
        __bf16* Kbf = (__bf16*)(ws + KBF_OFF);
        __bf16* Vtg = (__bf16*)(ws + VTG_OFF);
        p01_state<<<dim3(256),  dim3(512), 0, stream>>>(K, V, Kbf, Vtg, G);
        p2_prefix<<<dim3(2560), dim3(256), 0, stream>>>(G, Hb);
        p3_attend<<<dim3(512),  dim3(256), 0, stream>>>(Q, Kbf, Vtg, Hb, O);
    } else {
        taylor_mono<<<dim3(512), dim3(128), 0, stream>>>(Q, K, V, O);
    }
}